// Round 15
// baseline (621.229 us; speedup 1.0000x reference)
//
#include <hip/hip_runtime.h>
#include <cstdint>
#include <cstddef>

// Problem constants (fixed by the reference).
#define NN   204800     // nodes
#define EE   3276800    // edges
#define BB   4096       // graphs
#define GS   50         // nodes per graph (contiguous blocks of 50)
#define NBUCK 200       // CSR sort buckets: 1024 nodes each
#define CHUNK 8192      // edges per pass1 block (400 blocks exactly)
#define BCAP  17408     // fixed bucket capacity: mean 16384 + >8 sigma
#define ESLOTS ((size_t)NBUCK * BCAP)   // padded edge-slot space (3,481,600)

typedef __attribute__((ext_vector_type(8))) short short8v;   // 8 bf16 (4 VGPR)
typedef __attribute__((ext_vector_type(4))) float f32x4;     // MFMA acc

__device__ __forceinline__ float bf2f(unsigned short u) {
  unsigned int x = ((unsigned int)u) << 16;
  return __int_as_float((int)x);
}
__device__ __forceinline__ unsigned short f2bf(float f) {
  unsigned int x = __float_as_uint(f);
  unsigned int r = (x + 0x7fffu + ((x >> 16) & 1u)) >> 16;   // RTN-even
  return (unsigned short)r;
}

struct P1Sh {
  int2 stage[CHUNK];                 // 64 KB
  unsigned char bid[CHUNK];          // 8 KB
  int hist[NBUCK], cur[NBUCK], lo[NBUCK], gbase[NBUCK];
  int sc[256];
};
struct TfSh { float C[64][129]; };   // 33 KB

// ---------------------------------------------------------------------------
// FUSED: transform_l0 (blocks where bid%9!=0) + pass1 (bid%9==0).
// 3600 blocks = 3200 transform + 400 pass1, interleaved for co-residency.
// transform_l0: x[N,64] f32 -> in-reg bf16 hi/lo -> @Wcat0[64,128] -> Tb0 bf16.
// pass1: LDS counting-sort of an 8192-edge chunk by bucket (dst>>10),
//        coalesced flush to fixed-capacity bucket regions in staging.
// staging lives in the hcat region (hcat dead until aggregate_l0).
// ---------------------------------------------------------------------------
__global__ __launch_bounds__(256) void fused_tp1_kernel(
    const float* __restrict__ x,
    const unsigned short* __restrict__ Whi, const unsigned short* __restrict__ Wlo,
    unsigned short* __restrict__ Tb0,
    const int* __restrict__ src, const int* __restrict__ dst,
    const int* __restrict__ etype, const float* __restrict__ en,
    int* __restrict__ gcursor, int2* __restrict__ staging) {
  __shared__ union { P1Sh p1; TfSh tf; } sh;
  const int tid = threadIdx.x;

  if (blockIdx.x % 9 != 0) {
    // ------------------------- transform_l0 -------------------------
    const int tb = blockIdx.x - blockIdx.x / 9 - 1;      // 0..3199
    const int wv = tid >> 6, l = tid & 63;
    const int l15 = l & 15, kg = l >> 4;
    const int row = tb * 64 + wv * 16 + l15;

    short8v ah[2], al[2];
#pragma unroll
    for (int q = 0; q < 2; ++q) {
      const float* xp = x + (size_t)row * 64 + q * 32 + kg * 8;
      const float4 v0 = *reinterpret_cast<const float4*>(xp);
      const float4 v1 = *reinterpret_cast<const float4*>(xp + 4);
      const float vv[8] = {v0.x, v0.y, v0.z, v0.w, v1.x, v1.y, v1.z, v1.w};
#pragma unroll
      for (int f = 0; f < 8; ++f) {
        const unsigned short h = f2bf(vv[f]);
        ah[q][f] = (short)h;
        al[q][f] = (short)f2bf(vv[f] - bf2f(h));
      }
    }

#pragma unroll
    for (int c = 0; c < 8; ++c) {
      f32x4 a = {0.f, 0.f, 0.f, 0.f};
#pragma unroll
      for (int q = 0; q < 2; ++q) {
        const size_t fb = ((size_t)(q * 8 + c) * 64 + l) * 8;
        const short8v bh = *reinterpret_cast<const short8v*>(Whi + fb);
        const short8v bl = *reinterpret_cast<const short8v*>(Wlo + fb);
        a = __builtin_amdgcn_mfma_f32_16x16x32_bf16(ah[q], bh, a, 0, 0, 0);
        a = __builtin_amdgcn_mfma_f32_16x16x32_bf16(al[q], bh, a, 0, 0, 0);
        a = __builtin_amdgcn_mfma_f32_16x16x32_bf16(ah[q], bl, a, 0, 0, 0);
      }
      // C/D layout [verified]: col = lane&15, row_in_tile = (lane>>4)*4 + reg
#pragma unroll
      for (int r = 0; r < 4; ++r)
        sh.tf.C[wv * 16 + kg * 4 + r][c * 16 + l15] = a[r];
    }
    __syncthreads();

    const int row64 = tid & 63, q = tid >> 6;
    const int node = tb * 64 + row64;
#pragma unroll
    for (int v = 0; v < 4; ++v) {
      const int cb = q * 32 + v * 8;
      uint4 pk;
      pk.x = (unsigned)f2bf(sh.tf.C[row64][cb + 0]) | ((unsigned)f2bf(sh.tf.C[row64][cb + 1]) << 16);
      pk.y = (unsigned)f2bf(sh.tf.C[row64][cb + 2]) | ((unsigned)f2bf(sh.tf.C[row64][cb + 3]) << 16);
      pk.z = (unsigned)f2bf(sh.tf.C[row64][cb + 4]) | ((unsigned)f2bf(sh.tf.C[row64][cb + 5]) << 16);
      pk.w = (unsigned)f2bf(sh.tf.C[row64][cb + 6]) | ((unsigned)f2bf(sh.tf.C[row64][cb + 7]) << 16);
      *reinterpret_cast<uint4*>(Tb0 + (size_t)node * 128 + cb) = pk;
    }
    return;
  }

  // ----------------------------- pass1 ------------------------------
  const int pb = blockIdx.x / 9;                         // 0..399
  const int ebase = pb * CHUNK;

  for (int i = tid; i < NBUCK; i += 256) sh.p1.hist[i] = 0;
  __syncthreads();
  for (int i = tid; i < CHUNK; i += 256) {
    int bk = dst[ebase + i] >> 10;
    sh.p1.bid[i] = (unsigned char)bk;
    atomicAdd(&sh.p1.hist[bk], 1);
  }
  __syncthreads();
  int hv = (tid < NBUCK) ? sh.p1.hist[tid] : 0;
  sh.p1.sc[tid] = hv;
  __syncthreads();
  for (int off = 1; off < 256; off <<= 1) {
    int t = (tid >= off) ? sh.p1.sc[tid - off] : 0;
    __syncthreads();
    sh.p1.sc[tid] += t;
    __syncthreads();
  }
  if (tid < NBUCK) {
    int excl = sh.p1.sc[tid] - hv;
    sh.p1.lo[tid]  = excl;
    sh.p1.cur[tid] = excl;
    sh.p1.gbase[tid] = hv ? atomicAdd(&gcursor[tid], hv) : 0;
  }
  __syncthreads();
  for (int i = tid; i < CHUNK; i += 256) {
    int bk = sh.p1.bid[i];
    int p = atomicAdd(&sh.p1.cur[bk], 1);
    int s  = src[ebase + i];
    int et = etype[ebase + i];
    int d  = dst[ebase + i];
    int2 r;
    r.x = (s << 12) | (et << 10) | (d & 1023);
    r.y = __float_as_int(en[ebase + i]);
    sh.p1.stage[p] = r;
  }
  __syncthreads();
  const int wave = tid >> 6, lane = tid & 63;
  for (int bk = wave; bk < NBUCK; bk += 4) {
    const int len = sh.p1.hist[bk];
    const int l0  = sh.p1.lo[bk];
    const int gb  = sh.p1.gbase[bk];
    for (int i = lane; i < len; i += 64)
      staging[gb + i] = sh.p1.stage[l0 + i];
  }
}

// ---------------------------------------------------------------------------
// pass2: per-bucket node hist+scan -> begs/ends, L2-window scatter into the
// PADDED slot space [b*BCAP, b*BCAP+cnt): offs[] (src*256+et*64) + norms[] bf16.
// (offs/norms MUST be sized ESLOTS = NBUCK*BCAP, not EE — round-14 bug.)
// ---------------------------------------------------------------------------
__global__ __launch_bounds__(256) void pass2_kernel(const int2* __restrict__ staging,
                                                    const int* __restrict__ gcursor,
                                                    int* __restrict__ begs,
                                                    int* __restrict__ ends,
                                                    int* __restrict__ offs,
                                                    unsigned short* __restrict__ norms) {
  __shared__ int lhist[1024];
  __shared__ int lcur[1024];
  __shared__ int psum[256];
  const int b = blockIdx.x;
  const int tid = threadIdx.x;
  const int base = b * BCAP;
  const int cnt  = gcursor[b] - base;

  for (int i = tid; i < 1024; i += 256) lhist[i] = 0;
  __syncthreads();
  for (int i = tid; i < cnt; i += 256)
    atomicAdd(&lhist[staging[base + i].x & 1023], 1);
  __syncthreads();
  int s0 = lhist[4 * tid], s1 = lhist[4 * tid + 1];
  int s2 = lhist[4 * tid + 2], s3 = lhist[4 * tid + 3];
  int tot = s0 + s1 + s2 + s3;
  psum[tid] = tot;
  __syncthreads();
  for (int off = 1; off < 256; off <<= 1) {
    int t = (tid >= off) ? psum[tid - off] : 0;
    __syncthreads();
    psum[tid] += t;
    __syncthreads();
  }
  int o0 = base + psum[tid] - tot;
  int o1 = o0 + s0, o2 = o1 + s1, o3 = o2 + s2;
  const int nodeb = b * 1024;
  begs[nodeb + 4 * tid]     = o0;  ends[nodeb + 4 * tid]     = o1;  lcur[4 * tid]     = o0;
  begs[nodeb + 4 * tid + 1] = o1;  ends[nodeb + 4 * tid + 1] = o2;  lcur[4 * tid + 1] = o1;
  begs[nodeb + 4 * tid + 2] = o2;  ends[nodeb + 4 * tid + 2] = o3;  lcur[4 * tid + 2] = o2;
  begs[nodeb + 4 * tid + 3] = o3;  ends[nodeb + 4 * tid + 3] = o3 + s3;  lcur[4 * tid + 3] = o3;
  __syncthreads();
  for (int i = tid; i < cnt; i += 256) {
    int2 r = staging[base + i];
    int pos = atomicAdd(&lcur[r.x & 1023], 1);
    int s  = r.x >> 12;
    int et = (r.x >> 10) & 3;
    offs[pos]  = (s << 8) + (et << 6);          // src*256 + et*64
    norms[pos] = f2bf(__int_as_float(r.y));
  }
}

// ---------------------------------------------------------------------------
// Weight prep (+ gcursor init piggybacked on block 0):
//   Wcat0 [64,128] | WcatR[3][32,128] | Mt [2][128][128] = 0.125*wp@wt^T |
//   W1c [256][64] = Wp-block @ w1
// ---------------------------------------------------------------------------
__global__ __launch_bounds__(256) void wprep_kernel(
    const float* __restrict__ bases0, const float* __restrict__ coef0,
    const float* __restrict__ wself0,
    const float* __restrict__ bases_r, const float* __restrict__ coef_r,
    const float* __restrict__ wself_r,
    const float* __restrict__ wp_u, const float* __restrict__ wp_i,
    const float* __restrict__ wt_u, const float* __restrict__ wt_i,
    const float* __restrict__ w1,
    float* __restrict__ Wbuf, int* __restrict__ gcursor) {
  if (blockIdx.x == 0 && threadIdx.x < NBUCK)
    gcursor[threadIdx.x] = threadIdx.x * BCAP;
  int idx = blockIdx.x * 256 + threadIdx.x;
  if (idx < 8192) {                                      // Wcat0: [64][128]
    int i = idx >> 7, j = idx & 127;
    float v;
    if (j < 96) {
      int r = j >> 5, f = j & 31;
      v = coef0[r * 2 + 0] * bases0[0 * 2048 + i * 32 + f]
        + coef0[r * 2 + 1] * bases0[1 * 2048 + i * 32 + f];
    } else {
      v = wself0[i * 32 + (j - 96)];
    }
    Wbuf[idx] = v;
    return;
  }
  int idx2 = idx - 8192;
  if (idx2 < 3 * 4096) {                                 // WcatR[l]: [32][128]
    int l = idx2 >> 12, rem = idx2 & 4095;
    int i = rem >> 7, j = rem & 127;
    float v;
    if (j < 96) {
      int r = j >> 5, f = j & 31;
      v = coef_r[l * 6 + r * 2 + 0] * bases_r[l * 2048 + 0 * 1024 + i * 32 + f]
        + coef_r[l * 6 + r * 2 + 1] * bases_r[l * 2048 + 1 * 1024 + i * 32 + f];
    } else {
      v = wself_r[l * 1024 + i * 32 + (j - 96)];
    }
    Wbuf[idx] = v;
    return;
  }
  int idx3 = idx2 - 12288;
  if (idx3 < 32768) {                                    // Mt[side][kk][k]
    int side = idx3 >> 14;
    int r = idx3 & 16383;
    int kk = r >> 7, k = r & 127;
    const float* wp = side ? wp_i : wp_u;
    const float* wt = side ? wt_i : wt_u;
    float acc = 0.f;
#pragma unroll 8
    for (int j = 0; j < 64; ++j)
      acc = fmaf(wp[k * 64 + j], wt[kk * 64 + j], acc);
    Wbuf[idx] = acc * 0.125f;                            // /sqrt(PH) folded
    return;
  }
  int idx4 = idx3 - 32768;
  if (idx4 < 16384) {                                    // W1c[k'][t]
    int kp = idx4 >> 6, t = idx4 & 63;
    int side = kp >> 7, k = kp & 127;
    const float* wp = side ? wp_i : wp_u;
    float acc = 0.f;
#pragma unroll 8
    for (int j = 0; j < 64; ++j)
      acc = fmaf(wp[k * 64 + j], w1[(side * 64 + j) * 64 + t], acc);
    Wbuf[idx] = acc;
  }
}

// wprep2: MFMA B-fragments, bf16 hi + residual lo (layouts as round 11).
__global__ __launch_bounds__(256) void wprep2_kernel(const float* __restrict__ Wbuf,
                                                     unsigned short* __restrict__ Whi,
                                                     unsigned short* __restrict__ Wlo) {
  int e = blockIdx.x * 256 + threadIdx.x;
  if (e >= 20480) return;
  float v;
  if (e < 8192) {                    // layer 0, K=64, 128 out cols
    int j = e & 7, l = (e >> 3) & 63, c = (e >> 9) & 7, q = e >> 12;
    int k   = q * 32 + (l >> 4) * 8 + j;
    int col = c * 16 + (l & 15);
    v = Wbuf[k * 128 + col];
  } else {                           // layers 1-3, K=128, 32 out cols
    int e2 = e - 8192;
    int lay = e2 >> 12, r = e2 & 4095;
    int j = r & 7, l = (r >> 3) & 63, qc = r >> 9;       // 0..7
    int q = qc >> 1, c = qc & 1;
    int k = q * 32 + (l >> 4) * 8 + j;                   // 0..127
    int o = c * 16 + (l & 15);                           // 0..31
    const float* Wc = Wbuf + 8192 + lay * 4096;          // WcatR[lay][32][128]
    v = (k < 96) ? Wc[(k & 31) * 128 + (k >> 5) * 32 + o]
                 : Wc[(k - 96) * 128 + 96 + o];
  }
  unsigned short hi = f2bf(v);
  Whi[e] = hi;
  Wlo[e] = f2bf(v - bf2f(hi));
}

// ---------------------------------------------------------------------------
// Layer-0 aggregate: gathers pre-transformed messages from Tb0 (64B/edge),
// adds bf16 self (row bytes [192,256)) + bias, tanh -> hcat slot0 + hbA.
// ---------------------------------------------------------------------------
__global__ __launch_bounds__(256) void aggregate_l0_kernel(
    const unsigned short* __restrict__ Tb0,
    const int* __restrict__ begs, const int* __restrict__ ends,
    const int* __restrict__ offs, const unsigned short* __restrict__ norms,
    const float* __restrict__ bias,
    float* __restrict__ hcat, unsigned short* __restrict__ hbA) {
  const int node = blockIdx.x * 32 + (threadIdx.x >> 3);
  const int f4   = (threadIdx.x & 7) * 4;
  const int loff = f4 * 2;
  const char* Tbc = (const char*)Tb0;
  const int beg = begs[node];
  const int end = ends[node];
  const ushort4 sb = *reinterpret_cast<const ushort4*>(Tbc + (size_t)node * 256 + 192 + loff);
  const float4 bv  = *reinterpret_cast<const float4*>(&bias[f4]);
  float ax = bf2f(sb.x) + bv.x, ay = bf2f(sb.y) + bv.y;
  float az = bf2f(sb.z) + bv.z, aw = bf2f(sb.w) + bv.w;

  int k = beg;
  for (; k + 8 <= end; k += 8) {
    int od[8]; unsigned short nb[8];
#pragma unroll
    for (int u = 0; u < 8; ++u) od[u] = __builtin_nontemporal_load(offs + k + u);
#pragma unroll
    for (int u = 0; u < 8; ++u) nb[u] = __builtin_nontemporal_load(norms + k + u);
    ushort4 mv[8];
#pragma unroll
    for (int u = 0; u < 8; ++u)
      mv[u] = *reinterpret_cast<const ushort4*>(Tbc + od[u] + loff);
#pragma unroll
    for (int u = 0; u < 8; ++u) {
      const float nm = bf2f(nb[u]);
      ax = fmaf(bf2f(mv[u].x), nm, ax);
      ay = fmaf(bf2f(mv[u].y), nm, ay);
      az = fmaf(bf2f(mv[u].z), nm, az);
      aw = fmaf(bf2f(mv[u].w), nm, aw);
    }
  }
  for (; k < end; ++k) {
    const int od = offs[k];
    const float nm = bf2f(norms[k]);
    ushort4 m0 = *reinterpret_cast<const ushort4*>(Tbc + od + loff);
    ax = fmaf(bf2f(m0.x), nm, ax);
    ay = fmaf(bf2f(m0.y), nm, ay);
    az = fmaf(bf2f(m0.z), nm, az);
    aw = fmaf(bf2f(m0.w), nm, aw);
  }
  float4 o;
  o.x = tanhf(ax); o.y = tanhf(ay); o.z = tanhf(az); o.w = tanhf(aw);
  *reinterpret_cast<float4*>(&hcat[(size_t)node * 128 + f4]) = o;
  ushort4 h;
  h.x = f2bf(o.x); h.y = f2bf(o.y); h.z = f2bf(o.z); h.w = f2bf(o.w);
  *reinterpret_cast<ushort4*>(hbA + (size_t)node * 32 + f4) = h;
}

// ---------------------------------------------------------------------------
// FUSED layers 1-3: 32 nodes/block, 8 lanes/node gather from compact
// hbX [N][32]b (13MB table; nt streams protect its L2 residency),
// per-relation sums -> LDS bf16 [32][136]; MFMA [128->32] (W hi/lo);
// tanh+bias -> hcat slot (+ next hbY).
// ---------------------------------------------------------------------------
__global__ __launch_bounds__(256, 8) void agg_tf_kernel(
    const unsigned short* __restrict__ hbX,
    const int* __restrict__ begs, const int* __restrict__ ends,
    const int* __restrict__ offs, const unsigned short* __restrict__ norms,
    const unsigned short* __restrict__ Whi, const unsigned short* __restrict__ Wlo,
    const float* __restrict__ bias,
    float* __restrict__ hcatSlot, unsigned short* __restrict__ hbY) {
  __shared__ __align__(16) unsigned short sld[32][136];
  __shared__ float C[32][33];
  const int tid = threadIdx.x;

  // ---- phase A: 8 lanes/node, 4 features (8B) each ----
  {
    const int nl   = tid >> 3;                 // 0..31
    const int node = blockIdx.x * 32 + nl;
    const int f4   = (tid & 7) * 4;
    const int loff = f4 * 2;
    const char* hbc = (const char*)hbX;
    const int beg = begs[node], end = ends[node];
    float a0x = 0.f, a0y = 0.f, a0z = 0.f, a0w = 0.f;
    float a1x = 0.f, a1y = 0.f, a1z = 0.f, a1w = 0.f;
    float a2x = 0.f, a2y = 0.f, a2z = 0.f, a2w = 0.f;

    int k = beg;
    for (; k + 8 <= end; k += 8) {
      int od[8]; unsigned short nb[8];
#pragma unroll
      for (int u = 0; u < 8; ++u) od[u] = __builtin_nontemporal_load(offs + k + u);
#pragma unroll
      for (int u = 0; u < 8; ++u) nb[u] = __builtin_nontemporal_load(norms + k + u);
      ushort4 mv[8];
#pragma unroll
      for (int u = 0; u < 8; ++u)
        mv[u] = *reinterpret_cast<const ushort4*>(hbc + ((od[u] >> 2) & ~63) + loff);
#pragma unroll
      for (int u = 0; u < 8; ++u) {
        const int et = (od[u] >> 6) & 3;
        const float nm = bf2f(nb[u]);
        const float n0 = (et == 0) ? nm : 0.f;
        const float n1 = (et == 1) ? nm : 0.f;
        const float n2 = (et == 2) ? nm : 0.f;
        const float vx = bf2f(mv[u].x), vy = bf2f(mv[u].y);
        const float vz = bf2f(mv[u].z), vw = bf2f(mv[u].w);
        a0x = fmaf(vx, n0, a0x); a0y = fmaf(vy, n0, a0y);
        a0z = fmaf(vz, n0, a0z); a0w = fmaf(vw, n0, a0w);
        a1x = fmaf(vx, n1, a1x); a1y = fmaf(vy, n1, a1y);
        a1z = fmaf(vz, n1, a1z); a1w = fmaf(vw, n1, a1w);
        a2x = fmaf(vx, n2, a2x); a2y = fmaf(vy, n2, a2y);
        a2z = fmaf(vz, n2, a2z); a2w = fmaf(vw, n2, a2w);
      }
    }
    for (; k < end; ++k) {
      const int od = offs[k];
      const int et = (od >> 6) & 3;
      const float nm = bf2f(norms[k]);
      const float n0 = (et == 0) ? nm : 0.f;
      const float n1 = (et == 1) ? nm : 0.f;
      const float n2 = (et == 2) ? nm : 0.f;
      ushort4 m0 = *reinterpret_cast<const ushort4*>(hbc + ((od >> 2) & ~63) + loff);
      const float vx = bf2f(m0.x), vy = bf2f(m0.y), vz = bf2f(m0.z), vw = bf2f(m0.w);
      a0x = fmaf(vx, n0, a0x); a0y = fmaf(vy, n0, a0y);
      a0z = fmaf(vz, n0, a0z); a0w = fmaf(vw, n0, a0w);
      a1x = fmaf(vx, n1, a1x); a1y = fmaf(vy, n1, a1y);
      a1z = fmaf(vz, n1, a1z); a1w = fmaf(vw, n1, a1w);
      a2x = fmaf(vx, n2, a2x); a2y = fmaf(vy, n2, a2y);
      a2z = fmaf(vz, n2, a2z); a2w = fmaf(vw, n2, a2w);
    }
    ushort4 s0, s1, s2;
    s0.x = f2bf(a0x); s0.y = f2bf(a0y); s0.z = f2bf(a0z); s0.w = f2bf(a0w);
    s1.x = f2bf(a1x); s1.y = f2bf(a1y); s1.z = f2bf(a1z); s1.w = f2bf(a1w);
    s2.x = f2bf(a2x); s2.y = f2bf(a2y); s2.z = f2bf(a2z); s2.w = f2bf(a2w);
    *reinterpret_cast<ushort4*>(&sld[nl][f4])      = s0;
    *reinterpret_cast<ushort4*>(&sld[nl][32 + f4]) = s1;
    *reinterpret_cast<ushort4*>(&sld[nl][64 + f4]) = s2;
    *reinterpret_cast<ushort4*>(&sld[nl][96 + f4]) =
        *reinterpret_cast<const ushort4*>(hbX + (size_t)node * 32 + f4);
  }
  __syncthreads();

  // ---- phase B: 4 waves, wave w -> (row-half w&1, c-tile w>>1) ----
  {
    const int w = tid >> 6, l = tid & 63;
    const int rg = w & 1, c = w >> 1;
    const int l15 = l & 15, kg = l >> 4;
    const int row = rg * 16 + l15;
    short8v af[4];
#pragma unroll
    for (int q = 0; q < 4; ++q)
      af[q] = *reinterpret_cast<const short8v*>(&sld[row][q * 32 + kg * 8]);
    f32x4 a = {0.f, 0.f, 0.f, 0.f};
#pragma unroll
    for (int q = 0; q < 4; ++q) {
      const size_t fb = ((size_t)(q * 2 + c) * 64 + l) * 8;
      const short8v bh = *reinterpret_cast<const short8v*>(Whi + fb);
      const short8v bl = *reinterpret_cast<const short8v*>(Wlo + fb);
      a = __builtin_amdgcn_mfma_f32_16x16x32_bf16(af[q], bh, a, 0, 0, 0);
      a = __builtin_amdgcn_mfma_f32_16x16x32_bf16(af[q], bl, a, 0, 0, 0);
    }
    // C/D layout [verified]: col = lane&15, row_in_tile = (lane>>4)*4 + reg
#pragma unroll
    for (int r = 0; r < 4; ++r)
      C[rg * 16 + kg * 4 + r][c * 16 + l15] = a[r];
  }
  __syncthreads();

  // ---- epilogue: tanh + bias -> hcat slot (+ next hb) ----
  {
    const int row32 = tid & 31, g = tid >> 5;  // g: 4-col group 0..7
    const int node = blockIdx.x * 32 + row32;
    float z[4];
#pragma unroll
    for (int v = 0; v < 4; ++v)
      z[v] = tanhf(C[row32][g * 4 + v] + bias[g * 4 + v]);
    float4 f0 = {z[0], z[1], z[2], z[3]};
    *reinterpret_cast<float4*>(hcatSlot + (size_t)node * 128 + g * 4) = f0;
    if (hbY) {
      ushort4 pk;
      pk.x = f2bf(z[0]); pk.y = f2bf(z[1]); pk.z = f2bf(z[2]); pk.w = f2bf(z[3]);
      *reinterpret_cast<ushort4*>(hbY + (size_t)node * 32 + g * 4) = pk;
    }
  }
}

// ---------------------------------------------------------------------------
// Fused per-graph tail (unchanged; XCD-chunked graph swizzle).
// ---------------------------------------------------------------------------
__global__ __launch_bounds__(256) void pool_head_kernel(
    const float* __restrict__ hcat, const int* __restrict__ ntype,
    const float* __restrict__ Mt,   // [2][128][128], 0.125 folded
    const float* __restrict__ W1c,  // [256][64]
    const float* __restrict__ b1,
    const float* __restrict__ w2, const float* __restrict__ b2,
    float* __restrict__ out, float* __restrict__ tl) {
  __shared__ float hl[GS * 129];
  __shared__ float scr[1024];
  __shared__ float av2[256];
  __shared__ float red[4];
  __shared__ float cnts[4];
  __shared__ int   snt[64];
  __shared__ int   sntp[64];

  const int g    = (blockIdx.x & 7) * (BB / 8) + (blockIdx.x >> 3);  // XCD chunk
  const int gp   = (g + BB - 1) & (BB - 1);
  const int tid  = threadIdx.x;
  const int lane = tid & 63;

  const float* hg  = hcat + (size_t)g  * (GS * 128);
  const float* hp  = hcat + (size_t)gp * (GS * 128);
  const int*   ntg = ntype + g  * GS;
  const int*   ntp = ntype + gp * GS;

  if (tid < 64) {
    snt[tid] = (tid < GS) ? ntg[tid] : 99;
    unsigned long long bu = __ballot(snt[tid] == 0);
    unsigned long long bi = __ballot(snt[tid] == 1);
    if (lane == 0) {
      cnts[0] = 1.f / ((float)__popcll(bu) + 1e-8f);
      cnts[1] = 1.f / ((float)__popcll(bi) + 1e-8f);
    }
  } else if (tid < 128) {
    sntp[lane] = (lane < GS) ? ntp[lane] : 99;
    unsigned long long bp = __ballot(sntp[lane] == 1);
    if (lane == 0) cnts[2] = 1.f / ((float)__popcll(bp) + 1e-8f);
  }

  {
    const int rowg = tid >> 5;
    const int kq   = (tid & 31) * 4;
    float spx = 0.f, spy = 0.f, spz = 0.f, spw = 0.f;
#pragma unroll
    for (int p = 0; p < 7; ++p) {
      const int r = rowg + 8 * p;
      if (r < GS) {
        const float4 v = *reinterpret_cast<const float4*>(hg + r * 128 + kq);
        hl[r * 129 + kq + 0] = v.x;
        hl[r * 129 + kq + 1] = v.y;
        hl[r * 129 + kq + 2] = v.z;
        hl[r * 129 + kq + 3] = v.w;
        if (ntp[r] == 1) {
          const float4 w = *reinterpret_cast<const float4*>(hp + r * 128 + kq);
          spx += w.x; spy += w.y; spz += w.z; spw += w.w;
        }
      }
    }
    scr[rowg * 128 + kq + 0] = spx;
    scr[rowg * 128 + kq + 1] = spy;
    scr[rowg * 128 + kq + 2] = spz;
    scr[rowg * 128 + kq + 3] = spw;
  }
  __syncthreads();

  if (tid < 128) {
    const int kf = tid;
    float su = 0.f, si = 0.f;
#pragma unroll
    for (int r = 0; r < GS; ++r) {
      const float v = hl[r * 129 + kf];
      if (snt[r] == 0) su += v; else si += v;
    }
    float sp = 0.f;
#pragma unroll
    for (int rg = 0; rg < 8; ++rg) sp += scr[rg * 128 + kf];
    const float auk = su * cnts[0];
    const float aik = si * cnts[1];
    const float apk = sp * cnts[2];
    av2[kf]       = auk;
    av2[128 + kf] = aik;
    float d1 = (auk - aik) * (auk - aik);
    float d2 = (auk - apk) * (auk - apk);
    for (int o = 32; o; o >>= 1) {
      d1 += __shfl_xor(d1, o);
      d2 += __shfl_xor(d2, o);
    }
    if (lane == 0) { red[tid >> 6] = d1; red[2 + (tid >> 6)] = d2; }
  }
  __syncthreads();

  {
    const int side = tid >> 7, kf = tid & 127;
    const float* M  = Mt + (size_t)side * 16384 + kf;
    const float* av = av2 + side * 128;
    float a0 = 0.f, a1 = 0.f, a2 = 0.f, a3 = 0.f;
#pragma unroll 4
    for (int kk = 0; kk < 128; kk += 4) {
      a0 = fmaf(M[(kk + 0) * 128], av[kk + 0], a0);
      a1 = fmaf(M[(kk + 1) * 128], av[kk + 1], a1);
      a2 = fmaf(M[(kk + 2) * 128], av[kk + 2], a2);
      a3 = fmaf(M[(kk + 3) * 128], av[kk + 3], a3);
    }
    scr[tid] = (a0 + a1) + (a2 + a3);
  }
  if (tid == 0) tl[g] = fmaxf(0.f, (red[0] + red[1]) - (red[2] + red[3]) + 1.0f);
  __syncthreads();

  if (tid < 128) {
    const int side = tid >> 6;
    const float* q = scr + side * 128;
    float v = -1e9f;
    bool msk = false;
    if (lane < GS) {
      msk = (snt[lane] == side);
      float a0 = 0.f, a1 = 0.f;
#pragma unroll 8
      for (int k = 0; k < 128; k += 2) {
        a0 = fmaf(hl[lane * 129 + k], q[k], a0);
        a1 = fmaf(hl[lane * 129 + k + 1], q[k + 1], a1);
      }
      v = msk ? (a0 + a1) : -1e9f;
    }
    float m = v;
    for (int o = 32; o; o >>= 1) m = fmaxf(m, __shfl_xor(m, o));
    float e = (lane < GS && msk) ? expf(v - m) : 0.f;
    float z = e;
    for (int o = 32; o; o >>= 1) z += __shfl_xor(z, o);
    const float invz = 1.f / (z + 1e-8f);
    if (lane < GS) scr[256 + side * 64 + lane] = e * invz;
  }
  __syncthreads();

  {
    const int side = tid >> 7, kf = tid & 127;
    const float* a = scr + 256 + side * 64;
    float acc = 0.f;
#pragma unroll
    for (int nl = 0; nl < GS; ++nl)
      acc = fmaf(a[nl], hl[nl * 129 + kf], acc);
    scr[384 + side * 128 + kf] = acc;
  }
  __syncthreads();

  {
    const int j = tid & 63, c = tid >> 6;
    const float* Wc = W1c + (size_t)c * 64 * 64 + j;
    const float* cv = scr + 384 + c * 64;
    float a0 = 0.f, a1 = 0.f, a2 = 0.f, a3 = 0.f;
#pragma unroll 4
    for (int k = 0; k < 64; k += 4) {
      a0 = fmaf(Wc[(k + 0) * 64], cv[k + 0], a0);
      a1 = fmaf(Wc[(k + 1) * 64], cv[k + 1], a1);
      a2 = fmaf(Wc[(k + 2) * 64], cv[k + 2], a2);
      a3 = fmaf(Wc[(k + 3) * 64], cv[k + 3], a3);
    }
    scr[640 + c * 64 + j] = (a0 + a1) + (a2 + a3);
  }
  __syncthreads();

  if (tid < 64) {
    const float z1 = fmaxf(b1[tid] + scr[640 + tid] + scr[704 + tid] +
                           scr[768 + tid] + scr[832 + tid], 0.f);
    float p = z1 * w2[tid];
    for (int o = 32; o; o >>= 1) p += __shfl_xor(p, o);
    if (tid == 0) out[g] = 1.f / (1.f + expf(-(p + b2[0])));
  }
}

__global__ __launch_bounds__(256) void tl_reduce_kernel(const float* __restrict__ tl,
                                                        float* __restrict__ out) {
  __shared__ float s[256];
  float acc = 0.f;
  for (int i = threadIdx.x; i < BB; i += 256) acc += tl[i];
  s[threadIdx.x] = acc;
  __syncthreads();
  for (int off = 128; off > 0; off >>= 1) {
    if (threadIdx.x < off) s[threadIdx.x] += s[threadIdx.x + off];
    __syncthreads();
  }
  if (threadIdx.x == 0) out[BB] = s[0] * (1.f / (float)BB);
}

// ---------------------------------------------------------------------------
extern "C" void kernel_launch(void* const* d_in, const int* in_sizes, int n_in,
                              void* d_out, int out_size, void* d_ws, size_t ws_size,
                              hipStream_t stream) {
  const float* x        = (const float*)d_in[0];
  const float* edge_nrm = (const float*)d_in[1];
  const int*   src      = (const int*)d_in[2];
  const int*   dst      = (const int*)d_in[3];
  const int*   etype    = (const int*)d_in[4];
  // d_in[5] = graph_id: unused (contiguous 50-node graphs)
  const int*   ntype    = (const int*)d_in[6];
  const float* bases0   = (const float*)d_in[7];
  const float* coef0    = (const float*)d_in[8];
  const float* wself0   = (const float*)d_in[9];
  const float* bias0    = (const float*)d_in[10];
  const float* bases_r  = (const float*)d_in[11];
  const float* coef_r   = (const float*)d_in[12];
  const float* wself_r  = (const float*)d_in[13];
  const float* bias_r   = (const float*)d_in[14];
  const float* wp_u     = (const float*)d_in[15];
  const float* wt_u     = (const float*)d_in[16];
  const float* wp_i     = (const float*)d_in[17];
  const float* wt_i     = (const float*)d_in[18];
  const float* w1       = (const float*)d_in[19];
  const float* b1       = (const float*)d_in[20];
  const float* w2       = (const float*)d_in[21];
  const float* b2       = (const float*)d_in[22];
  float* out = (float*)d_out;

  // workspace layout (regions verified disjoint):
  //   hcat : N*128 f32 [0, N*512B)
  //          - head [0, 27.9MB) doubles as CSR 'staging' during the build
  //            (dead until aggregate_l0 writes hcat, which runs after pass2).
  //   R    : N*128 f32:
  //            Tb0 bf16 [0, N*256B) | hbA [N*256, N*320) | hbB [N*320, N*384)
  //   offs : ESLOTS int (PADDED slot space!) | norms: ESLOTS bf16 |
  //   begs,ends: N each | gcursor: 256 | Wbuf: 69632 f32 |
  //   Whi/Wlo: 2*20480 bf16 | tl: B
  float*          hcat = (float*)d_ws;                       // N*128
  int2*           staging = (int2*)hcat;                     // CSR-build alias
  float*          R    = hcat + (size_t)NN * 128;            // N*128
  unsigned short* Tb0  = (unsigned short*)R;                 // N*128 bf16
  unsigned short* hbA  = Tb0 + (size_t)NN * 128;             // N*32 bf16
  unsigned short* hbB  = hbA + (size_t)NN * 32;              // N*32 bf16
  int*            offs = (int*)(R + (size_t)NN * 128);       // ESLOTS int
  unsigned short* norms= (unsigned short*)(offs + ESLOTS);   // ESLOTS bf16
  int*   begs    = (int*)(norms + ESLOTS);                   // N
  int*   ends    = begs + NN;                                // N
  int*   gcursor = ends + NN;                                // 256
  float* Wbuf    = (float*)(gcursor + 256);                  // 69632 f32
  unsigned short* Whi = (unsigned short*)(Wbuf + 69632);     // 20480 bf16
  unsigned short* Wlo = Whi + 20480;                         // 20480 bf16
  float* tl      = Wbuf + 69632 + 10240;                     // B

  size_t need = ((size_t)NN * 128 * 2 + ESLOTS + ESLOTS / 2 + 2 * NN +
                 256 + 69632 + 10240 + BB) * 4;
  if (ws_size < need) return;

  // --- weights (+gcursor init) + MFMA fragment packing ---
  wprep_kernel<<<(69632 + 255) / 256, 256, 0, stream>>>(
      bases0, coef0, wself0, bases_r, coef_r, wself_r,
      wp_u, wp_i, wt_u, wt_i, w1, Wbuf, gcursor);
  wprep2_kernel<<<80, 256, 0, stream>>>(Wbuf, Whi, Wlo);

  // --- fused: transform_l0 (3200 blk) interleaved 8:1 with pass1 (400 blk) ---
  fused_tp1_kernel<<<NN / 64 + EE / CHUNK, 256, 0, stream>>>(
      x, Whi, Wlo, Tb0, src, dst, etype, edge_nrm, gcursor, staging);
  pass2_kernel<<<NBUCK, 256, 0, stream>>>(staging, gcursor, begs, ends,
                                          offs, norms);

  // --- layer 0 aggregate (gather Tb0) ---
  aggregate_l0_kernel<<<NN / 32, 256, 0, stream>>>(Tb0, begs, ends, offs, norms,
                                                   bias0, hcat, hbA);

  // --- layers 1..3: fused gather + per-relation sums + MFMA + tanh ---
  agg_tf_kernel<<<NN / 32, 256, 0, stream>>>(
      hbA, begs, ends, offs, norms, Whi + 8192, Wlo + 8192, bias_r,
      hcat + 32, hbB);
  agg_tf_kernel<<<NN / 32, 256, 0, stream>>>(
      hbB, begs, ends, offs, norms, Whi + 12288, Wlo + 12288, bias_r + 32,
      hcat + 64, hbA);
  agg_tf_kernel<<<NN / 32, 256, 0, stream>>>(
      hbA, begs, ends, offs, norms, Whi + 16384, Wlo + 16384, bias_r + 64,
      hcat + 96, nullptr);

  // --- fused per-graph tail ---
  pool_head_kernel<<<BB, 256, 0, stream>>>(hcat, ntype,
                                           Wbuf + 20480, Wbuf + 53248,
                                           b1, w2, b2, out, tl);
  tl_reduce_kernel<<<1, 256, 0, stream>>>(tl, out);
}

// Round 16
// 604.973 us; speedup vs baseline: 1.0269x; 1.0269x over previous
//
#include <hip/hip_runtime.h>
#include <cstdint>
#include <cstddef>

// Problem constants (fixed by the reference).
#define NN   204800     // nodes
#define EE   3276800    // edges
#define BB   4096       // graphs
#define GS   50         // nodes per graph (contiguous blocks of 50)
#define NBUCK 200       // CSR sort buckets: 1024 nodes each
#define CHUNK 8192      // edges per pass1 block (400 blocks exactly)
#define BCAP  17408     // fixed bucket capacity: mean 16384 + >8 sigma
#define ESLOTS ((size_t)NBUCK * BCAP)   // padded edge-slot space (3,481,600)

typedef __attribute__((ext_vector_type(8))) short short8v;   // 8 bf16 (4 VGPR)
typedef __attribute__((ext_vector_type(4))) float f32x4;     // MFMA acc

__device__ __forceinline__ float bf2f(unsigned short u) {
  unsigned int x = ((unsigned int)u) << 16;
  return __int_as_float((int)x);
}
__device__ __forceinline__ unsigned short f2bf(float f) {
  unsigned int x = __float_as_uint(f);
  unsigned int r = (x + 0x7fffu + ((x >> 16) & 1u)) >> 16;   // RTN-even
  return (unsigned short)r;
}

// ---------------------------------------------------------------------------
// pass1: LDS counting-sort of an 8192-edge chunk by bucket (dst>>10),
// coalesced flush to fixed-capacity bucket regions in staging.
// (Separate kernel: its 76.5KB LDS must NOT be charged to the transform —
//  round-15 union-fusion lesson.)
// ---------------------------------------------------------------------------
__global__ __launch_bounds__(256) void pass1_kernel(const int* __restrict__ src,
                                                    const int* __restrict__ dst,
                                                    const int* __restrict__ etype,
                                                    const float* __restrict__ en,
                                                    int* __restrict__ gcursor,
                                                    int2* __restrict__ staging) {
  __shared__ int2 stage[CHUNK];                 // 64 KB
  __shared__ unsigned char bid[CHUNK];          // 8 KB
  __shared__ int hist[NBUCK], cur[NBUCK], lo[NBUCK], gbase[NBUCK];
  __shared__ int sc[256];
  const int tid = threadIdx.x;
  const int ebase = blockIdx.x * CHUNK;

  for (int i = tid; i < NBUCK; i += 256) hist[i] = 0;
  __syncthreads();
  for (int i = tid; i < CHUNK; i += 256) {
    int bk = dst[ebase + i] >> 10;
    bid[i] = (unsigned char)bk;
    atomicAdd(&hist[bk], 1);
  }
  __syncthreads();
  int hv = (tid < NBUCK) ? hist[tid] : 0;
  sc[tid] = hv;
  __syncthreads();
  for (int off = 1; off < 256; off <<= 1) {
    int t = (tid >= off) ? sc[tid - off] : 0;
    __syncthreads();
    sc[tid] += t;
    __syncthreads();
  }
  if (tid < NBUCK) {
    int excl = sc[tid] - hv;
    lo[tid]  = excl;
    cur[tid] = excl;
    gbase[tid] = hv ? atomicAdd(&gcursor[tid], hv) : 0;
  }
  __syncthreads();
  for (int i = tid; i < CHUNK; i += 256) {
    int bk = bid[i];
    int p = atomicAdd(&cur[bk], 1);
    int s  = src[ebase + i];
    int et = etype[ebase + i];
    int d  = dst[ebase + i];
    int2 r;
    r.x = (s << 12) | (et << 10) | (d & 1023);
    r.y = __float_as_int(en[ebase + i]);
    stage[p] = r;
  }
  __syncthreads();
  const int wave = tid >> 6, lane = tid & 63;
  for (int bk = wave; bk < NBUCK; bk += 4) {
    const int len = hist[bk];
    const int l0  = lo[bk];
    const int gb  = gbase[bk];
    for (int i = lane; i < len; i += 64)
      staging[gb + i] = stage[l0 + i];
  }
}

// ---------------------------------------------------------------------------
// pass2: per-bucket node hist+scan -> begs/ends, L2-window scatter into the
// PADDED slot space [b*BCAP, b*BCAP+cnt): offs[] (src*256+et*64) + norms[] bf16.
// offs/norms are sized ESLOTS (padded), not EE.
// ---------------------------------------------------------------------------
__global__ __launch_bounds__(256) void pass2_kernel(const int2* __restrict__ staging,
                                                    const int* __restrict__ gcursor,
                                                    int* __restrict__ begs,
                                                    int* __restrict__ ends,
                                                    int* __restrict__ offs,
                                                    unsigned short* __restrict__ norms) {
  __shared__ int lhist[1024];
  __shared__ int lcur[1024];
  __shared__ int psum[256];
  const int b = blockIdx.x;
  const int tid = threadIdx.x;
  const int base = b * BCAP;
  const int cnt  = gcursor[b] - base;

  for (int i = tid; i < 1024; i += 256) lhist[i] = 0;
  __syncthreads();
  for (int i = tid; i < cnt; i += 256)
    atomicAdd(&lhist[staging[base + i].x & 1023], 1);
  __syncthreads();
  int s0 = lhist[4 * tid], s1 = lhist[4 * tid + 1];
  int s2 = lhist[4 * tid + 2], s3 = lhist[4 * tid + 3];
  int tot = s0 + s1 + s2 + s3;
  psum[tid] = tot;
  __syncthreads();
  for (int off = 1; off < 256; off <<= 1) {
    int t = (tid >= off) ? psum[tid - off] : 0;
    __syncthreads();
    psum[tid] += t;
    __syncthreads();
  }
  int o0 = base + psum[tid] - tot;
  int o1 = o0 + s0, o2 = o1 + s1, o3 = o2 + s2;
  const int nodeb = b * 1024;
  begs[nodeb + 4 * tid]     = o0;  ends[nodeb + 4 * tid]     = o1;  lcur[4 * tid]     = o0;
  begs[nodeb + 4 * tid + 1] = o1;  ends[nodeb + 4 * tid + 1] = o2;  lcur[4 * tid + 1] = o1;
  begs[nodeb + 4 * tid + 2] = o2;  ends[nodeb + 4 * tid + 2] = o3;  lcur[4 * tid + 2] = o2;
  begs[nodeb + 4 * tid + 3] = o3;  ends[nodeb + 4 * tid + 3] = o3 + s3;  lcur[4 * tid + 3] = o3;
  __syncthreads();
  for (int i = tid; i < cnt; i += 256) {
    int2 r = staging[base + i];
    int pos = atomicAdd(&lcur[r.x & 1023], 1);
    int s  = r.x >> 12;
    int et = (r.x >> 10) & 3;
    offs[pos]  = (s << 8) + (et << 6);          // src*256 + et*64
    norms[pos] = f2bf(__int_as_float(r.y));
  }
}

// ---------------------------------------------------------------------------
// Weight prep (+ gcursor init piggybacked on block 0):
//   Wcat0 [64,128] | WcatR[3][32,128] | Mt [2][128][128] = 0.125*wp@wt^T |
//   W1c [256][64] = Wp-block @ w1
// ---------------------------------------------------------------------------
__global__ __launch_bounds__(256) void wprep_kernel(
    const float* __restrict__ bases0, const float* __restrict__ coef0,
    const float* __restrict__ wself0,
    const float* __restrict__ bases_r, const float* __restrict__ coef_r,
    const float* __restrict__ wself_r,
    const float* __restrict__ wp_u, const float* __restrict__ wp_i,
    const float* __restrict__ wt_u, const float* __restrict__ wt_i,
    const float* __restrict__ w1,
    float* __restrict__ Wbuf, int* __restrict__ gcursor) {
  if (blockIdx.x == 0 && threadIdx.x < NBUCK)
    gcursor[threadIdx.x] = threadIdx.x * BCAP;
  int idx = blockIdx.x * 256 + threadIdx.x;
  if (idx < 8192) {                                      // Wcat0: [64][128]
    int i = idx >> 7, j = idx & 127;
    float v;
    if (j < 96) {
      int r = j >> 5, f = j & 31;
      v = coef0[r * 2 + 0] * bases0[0 * 2048 + i * 32 + f]
        + coef0[r * 2 + 1] * bases0[1 * 2048 + i * 32 + f];
    } else {
      v = wself0[i * 32 + (j - 96)];
    }
    Wbuf[idx] = v;
    return;
  }
  int idx2 = idx - 8192;
  if (idx2 < 3 * 4096) {                                 // WcatR[l]: [32][128]
    int l = idx2 >> 12, rem = idx2 & 4095;
    int i = rem >> 7, j = rem & 127;
    float v;
    if (j < 96) {
      int r = j >> 5, f = j & 31;
      v = coef_r[l * 6 + r * 2 + 0] * bases_r[l * 2048 + 0 * 1024 + i * 32 + f]
        + coef_r[l * 6 + r * 2 + 1] * bases_r[l * 2048 + 1 * 1024 + i * 32 + f];
    } else {
      v = wself_r[l * 1024 + i * 32 + (j - 96)];
    }
    Wbuf[idx] = v;
    return;
  }
  int idx3 = idx2 - 12288;
  if (idx3 < 32768) {                                    // Mt[side][kk][k]
    int side = idx3 >> 14;
    int r = idx3 & 16383;
    int kk = r >> 7, k = r & 127;
    const float* wp = side ? wp_i : wp_u;
    const float* wt = side ? wt_i : wt_u;
    float acc = 0.f;
#pragma unroll 8
    for (int j = 0; j < 64; ++j)
      acc = fmaf(wp[k * 64 + j], wt[kk * 64 + j], acc);
    Wbuf[idx] = acc * 0.125f;                            // /sqrt(PH) folded
    return;
  }
  int idx4 = idx3 - 32768;
  if (idx4 < 16384) {                                    // W1c[k'][t]
    int kp = idx4 >> 6, t = idx4 & 63;
    int side = kp >> 7, k = kp & 127;
    const float* wp = side ? wp_i : wp_u;
    float acc = 0.f;
#pragma unroll 8
    for (int j = 0; j < 64; ++j)
      acc = fmaf(wp[k * 64 + j], w1[(side * 64 + j) * 64 + t], acc);
    Wbuf[idx] = acc;
  }
}

// wprep2: MFMA B-fragments, bf16 hi + residual lo (layouts as round 11).
__global__ __launch_bounds__(256) void wprep2_kernel(const float* __restrict__ Wbuf,
                                                     unsigned short* __restrict__ Whi,
                                                     unsigned short* __restrict__ Wlo) {
  int e = blockIdx.x * 256 + threadIdx.x;
  if (e >= 20480) return;
  float v;
  if (e < 8192) {                    // layer 0, K=64, 128 out cols
    int j = e & 7, l = (e >> 3) & 63, c = (e >> 9) & 7, q = e >> 12;
    int k   = q * 32 + (l >> 4) * 8 + j;
    int col = c * 16 + (l & 15);
    v = Wbuf[k * 128 + col];
  } else {                           // layers 1-3, K=128, 32 out cols
    int e2 = e - 8192;
    int lay = e2 >> 12, r = e2 & 4095;
    int j = r & 7, l = (r >> 3) & 63, qc = r >> 9;       // 0..7
    int q = qc >> 1, c = qc & 1;
    int k = q * 32 + (l >> 4) * 8 + j;                   // 0..127
    int o = c * 16 + (l & 15);                           // 0..31
    const float* Wc = Wbuf + 8192 + lay * 4096;          // WcatR[lay][32][128]
    v = (k < 96) ? Wc[(k & 31) * 128 + (k >> 5) * 32 + o]
                 : Wc[(k - 96) * 128 + 96 + o];
  }
  unsigned short hi = f2bf(v);
  Whi[e] = hi;
  Wlo[e] = f2bf(v - bf2f(hi));
}

// ---------------------------------------------------------------------------
// Layer-0 MFMA transform: x[N,64] (f32, hi/lo split in-register) @
// Wcat0[64,128] -> Tb0 [N][128] bf16 (msgs [0,96), self [96,128)).
// 3-term: Ahi@Whi + Alo@Whi + Ahi@Wlo.  33 KB LDS, own kernel.
// ---------------------------------------------------------------------------
__global__ __launch_bounds__(256) void transform_l0_kernel(
    const float* __restrict__ x,
    const unsigned short* __restrict__ Whi, const unsigned short* __restrict__ Wlo,
    unsigned short* __restrict__ Tb0) {
  __shared__ float C[64][129];
  const int tid = threadIdx.x;
  const int wv = tid >> 6, l = tid & 63;
  const int l15 = l & 15, kg = l >> 4;
  const int row = blockIdx.x * 64 + wv * 16 + l15;

  short8v ah[2], al[2];
#pragma unroll
  for (int q = 0; q < 2; ++q) {
    const float* xp = x + (size_t)row * 64 + q * 32 + kg * 8;
    const float4 v0 = *reinterpret_cast<const float4*>(xp);
    const float4 v1 = *reinterpret_cast<const float4*>(xp + 4);
    const float vv[8] = {v0.x, v0.y, v0.z, v0.w, v1.x, v1.y, v1.z, v1.w};
#pragma unroll
    for (int f = 0; f < 8; ++f) {
      const unsigned short h = f2bf(vv[f]);
      ah[q][f] = (short)h;
      al[q][f] = (short)f2bf(vv[f] - bf2f(h));
    }
  }

#pragma unroll
  for (int c = 0; c < 8; ++c) {
    f32x4 a = {0.f, 0.f, 0.f, 0.f};
#pragma unroll
    for (int q = 0; q < 2; ++q) {
      const size_t fb = ((size_t)(q * 8 + c) * 64 + l) * 8;
      const short8v bh = *reinterpret_cast<const short8v*>(Whi + fb);
      const short8v bl = *reinterpret_cast<const short8v*>(Wlo + fb);
      a = __builtin_amdgcn_mfma_f32_16x16x32_bf16(ah[q], bh, a, 0, 0, 0);
      a = __builtin_amdgcn_mfma_f32_16x16x32_bf16(al[q], bh, a, 0, 0, 0);
      a = __builtin_amdgcn_mfma_f32_16x16x32_bf16(ah[q], bl, a, 0, 0, 0);
    }
    // C/D layout [verified]: col = lane&15, row_in_tile = (lane>>4)*4 + reg
#pragma unroll
    for (int r = 0; r < 4; ++r)
      C[wv * 16 + kg * 4 + r][c * 16 + l15] = a[r];
  }
  __syncthreads();

  const int row64 = tid & 63, q = tid >> 6;
  const int node = blockIdx.x * 64 + row64;
#pragma unroll
  for (int v = 0; v < 4; ++v) {
    const int cb = q * 32 + v * 8;
    uint4 pk;
    pk.x = (unsigned)f2bf(C[row64][cb + 0]) | ((unsigned)f2bf(C[row64][cb + 1]) << 16);
    pk.y = (unsigned)f2bf(C[row64][cb + 2]) | ((unsigned)f2bf(C[row64][cb + 3]) << 16);
    pk.z = (unsigned)f2bf(C[row64][cb + 4]) | ((unsigned)f2bf(C[row64][cb + 5]) << 16);
    pk.w = (unsigned)f2bf(C[row64][cb + 6]) | ((unsigned)f2bf(C[row64][cb + 7]) << 16);
    *reinterpret_cast<uint4*>(Tb0 + (size_t)node * 128 + cb) = pk;
  }
}

// ---------------------------------------------------------------------------
// Layer-0 aggregate: gathers pre-transformed messages from Tb0 (64B/edge),
// adds bf16 self (row bytes [192,256)) + bias, tanh -> hcat slot0 + hbA.
// ---------------------------------------------------------------------------
__global__ __launch_bounds__(256) void aggregate_l0_kernel(
    const unsigned short* __restrict__ Tb0,
    const int* __restrict__ begs, const int* __restrict__ ends,
    const int* __restrict__ offs, const unsigned short* __restrict__ norms,
    const float* __restrict__ bias,
    float* __restrict__ hcat, unsigned short* __restrict__ hbA) {
  const int node = blockIdx.x * 32 + (threadIdx.x >> 3);
  const int f4   = (threadIdx.x & 7) * 4;
  const int loff = f4 * 2;
  const char* Tbc = (const char*)Tb0;
  const int beg = begs[node];
  const int end = ends[node];
  const ushort4 sb = *reinterpret_cast<const ushort4*>(Tbc + (size_t)node * 256 + 192 + loff);
  const float4 bv  = *reinterpret_cast<const float4*>(&bias[f4]);
  float ax = bf2f(sb.x) + bv.x, ay = bf2f(sb.y) + bv.y;
  float az = bf2f(sb.z) + bv.z, aw = bf2f(sb.w) + bv.w;

  int k = beg;
  for (; k + 8 <= end; k += 8) {
    int od[8]; unsigned short nb[8];
#pragma unroll
    for (int u = 0; u < 8; ++u) od[u] = __builtin_nontemporal_load(offs + k + u);
#pragma unroll
    for (int u = 0; u < 8; ++u) nb[u] = __builtin_nontemporal_load(norms + k + u);
    ushort4 mv[8];
#pragma unroll
    for (int u = 0; u < 8; ++u)
      mv[u] = *reinterpret_cast<const ushort4*>(Tbc + od[u] + loff);
#pragma unroll
    for (int u = 0; u < 8; ++u) {
      const float nm = bf2f(nb[u]);
      ax = fmaf(bf2f(mv[u].x), nm, ax);
      ay = fmaf(bf2f(mv[u].y), nm, ay);
      az = fmaf(bf2f(mv[u].z), nm, az);
      aw = fmaf(bf2f(mv[u].w), nm, aw);
    }
  }
  for (; k < end; ++k) {
    const int od = offs[k];
    const float nm = bf2f(norms[k]);
    ushort4 m0 = *reinterpret_cast<const ushort4*>(Tbc + od + loff);
    ax = fmaf(bf2f(m0.x), nm, ax);
    ay = fmaf(bf2f(m0.y), nm, ay);
    az = fmaf(bf2f(m0.z), nm, az);
    aw = fmaf(bf2f(m0.w), nm, aw);
  }
  float4 o;
  o.x = tanhf(ax); o.y = tanhf(ay); o.z = tanhf(az); o.w = tanhf(aw);
  *reinterpret_cast<float4*>(&hcat[(size_t)node * 128 + f4]) = o;
  ushort4 h;
  h.x = f2bf(o.x); h.y = f2bf(o.y); h.z = f2bf(o.z); h.w = f2bf(o.w);
  *reinterpret_cast<ushort4*>(hbA + (size_t)node * 32 + f4) = h;
}

// ---------------------------------------------------------------------------
// FUSED layers 1-3: 32 nodes/block, 8 lanes/node gather from compact
// hbX [N][32]b (13MB table; nt streams protect its L2 residency),
// per-relation sums -> LDS bf16 [32][136]; MFMA [128->32] (W hi/lo);
// tanh+bias -> hcat slot (+ next hbY).
// ---------------------------------------------------------------------------
__global__ __launch_bounds__(256, 8) void agg_tf_kernel(
    const unsigned short* __restrict__ hbX,
    const int* __restrict__ begs, const int* __restrict__ ends,
    const int* __restrict__ offs, const unsigned short* __restrict__ norms,
    const unsigned short* __restrict__ Whi, const unsigned short* __restrict__ Wlo,
    const float* __restrict__ bias,
    float* __restrict__ hcatSlot, unsigned short* __restrict__ hbY) {
  __shared__ __align__(16) unsigned short sld[32][136];
  __shared__ float C[32][33];
  const int tid = threadIdx.x;

  // ---- phase A: 8 lanes/node, 4 features (8B) each ----
  {
    const int nl   = tid >> 3;                 // 0..31
    const int node = blockIdx.x * 32 + nl;
    const int f4   = (tid & 7) * 4;
    const int loff = f4 * 2;
    const char* hbc = (const char*)hbX;
    const int beg = begs[node], end = ends[node];
    float a0x = 0.f, a0y = 0.f, a0z = 0.f, a0w = 0.f;
    float a1x = 0.f, a1y = 0.f, a1z = 0.f, a1w = 0.f;
    float a2x = 0.f, a2y = 0.f, a2z = 0.f, a2w = 0.f;

    int k = beg;
    for (; k + 8 <= end; k += 8) {
      int od[8]; unsigned short nb[8];
#pragma unroll
      for (int u = 0; u < 8; ++u) od[u] = __builtin_nontemporal_load(offs + k + u);
#pragma unroll
      for (int u = 0; u < 8; ++u) nb[u] = __builtin_nontemporal_load(norms + k + u);
      ushort4 mv[8];
#pragma unroll
      for (int u = 0; u < 8; ++u)
        mv[u] = *reinterpret_cast<const ushort4*>(hbc + ((od[u] >> 2) & ~63) + loff);
#pragma unroll
      for (int u = 0; u < 8; ++u) {
        const int et = (od[u] >> 6) & 3;
        const float nm = bf2f(nb[u]);
        const float n0 = (et == 0) ? nm : 0.f;
        const float n1 = (et == 1) ? nm : 0.f;
        const float n2 = (et == 2) ? nm : 0.f;
        const float vx = bf2f(mv[u].x), vy = bf2f(mv[u].y);
        const float vz = bf2f(mv[u].z), vw = bf2f(mv[u].w);
        a0x = fmaf(vx, n0, a0x); a0y = fmaf(vy, n0, a0y);
        a0z = fmaf(vz, n0, a0z); a0w = fmaf(vw, n0, a0w);
        a1x = fmaf(vx, n1, a1x); a1y = fmaf(vy, n1, a1y);
        a1z = fmaf(vz, n1, a1z); a1w = fmaf(vw, n1, a1w);
        a2x = fmaf(vx, n2, a2x); a2y = fmaf(vy, n2, a2y);
        a2z = fmaf(vz, n2, a2z); a2w = fmaf(vw, n2, a2w);
      }
    }
    for (; k < end; ++k) {
      const int od = offs[k];
      const int et = (od >> 6) & 3;
      const float nm = bf2f(norms[k]);
      const float n0 = (et == 0) ? nm : 0.f;
      const float n1 = (et == 1) ? nm : 0.f;
      const float n2 = (et == 2) ? nm : 0.f;
      ushort4 m0 = *reinterpret_cast<const ushort4*>(hbc + ((od >> 2) & ~63) + loff);
      const float vx = bf2f(m0.x), vy = bf2f(m0.y), vz = bf2f(m0.z), vw = bf2f(m0.w);
      a0x = fmaf(vx, n0, a0x); a0y = fmaf(vy, n0, a0y);
      a0z = fmaf(vz, n0, a0z); a0w = fmaf(vw, n0, a0w);
      a1x = fmaf(vx, n1, a1x); a1y = fmaf(vy, n1, a1y);
      a1z = fmaf(vz, n1, a1z); a1w = fmaf(vw, n1, a1w);
      a2x = fmaf(vx, n2, a2x); a2y = fmaf(vy, n2, a2y);
      a2z = fmaf(vz, n2, a2z); a2w = fmaf(vw, n2, a2w);
    }
    ushort4 s0, s1, s2;
    s0.x = f2bf(a0x); s0.y = f2bf(a0y); s0.z = f2bf(a0z); s0.w = f2bf(a0w);
    s1.x = f2bf(a1x); s1.y = f2bf(a1y); s1.z = f2bf(a1z); s1.w = f2bf(a1w);
    s2.x = f2bf(a2x); s2.y = f2bf(a2y); s2.z = f2bf(a2z); s2.w = f2bf(a2w);
    *reinterpret_cast<ushort4*>(&sld[nl][f4])      = s0;
    *reinterpret_cast<ushort4*>(&sld[nl][32 + f4]) = s1;
    *reinterpret_cast<ushort4*>(&sld[nl][64 + f4]) = s2;
    *reinterpret_cast<ushort4*>(&sld[nl][96 + f4]) =
        *reinterpret_cast<const ushort4*>(hbX + (size_t)node * 32 + f4);
  }
  __syncthreads();

  // ---- phase B: 4 waves, wave w -> (row-half w&1, c-tile w>>1) ----
  {
    const int w = tid >> 6, l = tid & 63;
    const int rg = w & 1, c = w >> 1;
    const int l15 = l & 15, kg = l >> 4;
    const int row = rg * 16 + l15;
    short8v af[4];
#pragma unroll
    for (int q = 0; q < 4; ++q)
      af[q] = *reinterpret_cast<const short8v*>(&sld[row][q * 32 + kg * 8]);
    f32x4 a = {0.f, 0.f, 0.f, 0.f};
#pragma unroll
    for (int q = 0; q < 4; ++q) {
      const size_t fb = ((size_t)(q * 2 + c) * 64 + l) * 8;
      const short8v bh = *reinterpret_cast<const short8v*>(Whi + fb);
      const short8v bl = *reinterpret_cast<const short8v*>(Wlo + fb);
      a = __builtin_amdgcn_mfma_f32_16x16x32_bf16(af[q], bh, a, 0, 0, 0);
      a = __builtin_amdgcn_mfma_f32_16x16x32_bf16(af[q], bl, a, 0, 0, 0);
    }
    // C/D layout [verified]: col = lane&15, row_in_tile = (lane>>4)*4 + reg
#pragma unroll
    for (int r = 0; r < 4; ++r)
      C[rg * 16 + kg * 4 + r][c * 16 + l15] = a[r];
  }
  __syncthreads();

  // ---- epilogue: tanh + bias -> hcat slot (+ next hb) ----
  {
    const int row32 = tid & 31, g = tid >> 5;  // g: 4-col group 0..7
    const int node = blockIdx.x * 32 + row32;
    float z[4];
#pragma unroll
    for (int v = 0; v < 4; ++v)
      z[v] = tanhf(C[row32][g * 4 + v] + bias[g * 4 + v]);
    float4 f0 = {z[0], z[1], z[2], z[3]};
    *reinterpret_cast<float4*>(hcatSlot + (size_t)node * 128 + g * 4) = f0;
    if (hbY) {
      ushort4 pk;
      pk.x = f2bf(z[0]); pk.y = f2bf(z[1]); pk.z = f2bf(z[2]); pk.w = f2bf(z[3]);
      *reinterpret_cast<ushort4*>(hbY + (size_t)node * 32 + g * 4) = pk;
    }
  }
}

// ---------------------------------------------------------------------------
// Fused per-graph tail (unchanged; XCD-chunked graph swizzle).
// ---------------------------------------------------------------------------
__global__ __launch_bounds__(256) void pool_head_kernel(
    const float* __restrict__ hcat, const int* __restrict__ ntype,
    const float* __restrict__ Mt,   // [2][128][128], 0.125 folded
    const float* __restrict__ W1c,  // [256][64]
    const float* __restrict__ b1,
    const float* __restrict__ w2, const float* __restrict__ b2,
    float* __restrict__ out, float* __restrict__ tl) {
  __shared__ float hl[GS * 129];
  __shared__ float scr[1024];
  __shared__ float av2[256];
  __shared__ float red[4];
  __shared__ float cnts[4];
  __shared__ int   snt[64];
  __shared__ int   sntp[64];

  const int g    = (blockIdx.x & 7) * (BB / 8) + (blockIdx.x >> 3);  // XCD chunk
  const int gp   = (g + BB - 1) & (BB - 1);
  const int tid  = threadIdx.x;
  const int lane = tid & 63;

  const float* hg  = hcat + (size_t)g  * (GS * 128);
  const float* hp  = hcat + (size_t)gp * (GS * 128);
  const int*   ntg = ntype + g  * GS;
  const int*   ntp = ntype + gp * GS;

  if (tid < 64) {
    snt[tid] = (tid < GS) ? ntg[tid] : 99;
    unsigned long long bu = __ballot(snt[tid] == 0);
    unsigned long long bi = __ballot(snt[tid] == 1);
    if (lane == 0) {
      cnts[0] = 1.f / ((float)__popcll(bu) + 1e-8f);
      cnts[1] = 1.f / ((float)__popcll(bi) + 1e-8f);
    }
  } else if (tid < 128) {
    sntp[lane] = (lane < GS) ? ntp[lane] : 99;
    unsigned long long bp = __ballot(sntp[lane] == 1);
    if (lane == 0) cnts[2] = 1.f / ((float)__popcll(bp) + 1e-8f);
  }

  {
    const int rowg = tid >> 5;
    const int kq   = (tid & 31) * 4;
    float spx = 0.f, spy = 0.f, spz = 0.f, spw = 0.f;
#pragma unroll
    for (int p = 0; p < 7; ++p) {
      const int r = rowg + 8 * p;
      if (r < GS) {
        const float4 v = *reinterpret_cast<const float4*>(hg + r * 128 + kq);
        hl[r * 129 + kq + 0] = v.x;
        hl[r * 129 + kq + 1] = v.y;
        hl[r * 129 + kq + 2] = v.z;
        hl[r * 129 + kq + 3] = v.w;
        if (ntp[r] == 1) {
          const float4 w = *reinterpret_cast<const float4*>(hp + r * 128 + kq);
          spx += w.x; spy += w.y; spz += w.z; spw += w.w;
        }
      }
    }
    scr[rowg * 128 + kq + 0] = spx;
    scr[rowg * 128 + kq + 1] = spy;
    scr[rowg * 128 + kq + 2] = spz;
    scr[rowg * 128 + kq + 3] = spw;
  }
  __syncthreads();

  if (tid < 128) {
    const int kf = tid;
    float su = 0.f, si = 0.f;
#pragma unroll
    for (int r = 0; r < GS; ++r) {
      const float v = hl[r * 129 + kf];
      if (snt[r] == 0) su += v; else si += v;
    }
    float sp = 0.f;
#pragma unroll
    for (int rg = 0; rg < 8; ++rg) sp += scr[rg * 128 + kf];
    const float auk = su * cnts[0];
    const float aik = si * cnts[1];
    const float apk = sp * cnts[2];
    av2[kf]       = auk;
    av2[128 + kf] = aik;
    float d1 = (auk - aik) * (auk - aik);
    float d2 = (auk - apk) * (auk - apk);
    for (int o = 32; o; o >>= 1) {
      d1 += __shfl_xor(d1, o);
      d2 += __shfl_xor(d2, o);
    }
    if (lane == 0) { red[tid >> 6] = d1; red[2 + (tid >> 6)] = d2; }
  }
  __syncthreads();

  {
    const int side = tid >> 7, kf = tid & 127;
    const float* M  = Mt + (size_t)side * 16384 + kf;
    const float* av = av2 + side * 128;
    float a0 = 0.f, a1 = 0.f, a2 = 0.f, a3 = 0.f;
#pragma unroll 4
    for (int kk = 0; kk < 128; kk += 4) {
      a0 = fmaf(M[(kk + 0) * 128], av[kk + 0], a0);
      a1 = fmaf(M[(kk + 1) * 128], av[kk + 1], a1);
      a2 = fmaf(M[(kk + 2) * 128], av[kk + 2], a2);
      a3 = fmaf(M[(kk + 3) * 128], av[kk + 3], a3);
    }
    scr[tid] = (a0 + a1) + (a2 + a3);
  }
  if (tid == 0) tl[g] = fmaxf(0.f, (red[0] + red[1]) - (red[2] + red[3]) + 1.0f);
  __syncthreads();

  if (tid < 128) {
    const int side = tid >> 6;
    const float* q = scr + side * 128;
    float v = -1e9f;
    bool msk = false;
    if (lane < GS) {
      msk = (snt[lane] == side);
      float a0 = 0.f, a1 = 0.f;
#pragma unroll 8
      for (int k = 0; k < 128; k += 2) {
        a0 = fmaf(hl[lane * 129 + k], q[k], a0);
        a1 = fmaf(hl[lane * 129 + k + 1], q[k + 1], a1);
      }
      v = msk ? (a0 + a1) : -1e9f;
    }
    float m = v;
    for (int o = 32; o; o >>= 1) m = fmaxf(m, __shfl_xor(m, o));
    float e = (lane < GS && msk) ? expf(v - m) : 0.f;
    float z = e;
    for (int o = 32; o; o >>= 1) z += __shfl_xor(z, o);
    const float invz = 1.f / (z + 1e-8f);
    if (lane < GS) scr[256 + side * 64 + lane] = e * invz;
  }
  __syncthreads();

  {
    const int side = tid >> 7, kf = tid & 127;
    const float* a = scr + 256 + side * 64;
    float acc = 0.f;
#pragma unroll
    for (int nl = 0; nl < GS; ++nl)
      acc = fmaf(a[nl], hl[nl * 129 + kf], acc);
    scr[384 + side * 128 + kf] = acc;
  }
  __syncthreads();

  {
    const int j = tid & 63, c = tid >> 6;
    const float* Wc = W1c + (size_t)c * 64 * 64 + j;
    const float* cv = scr + 384 + c * 64;
    float a0 = 0.f, a1 = 0.f, a2 = 0.f, a3 = 0.f;
#pragma unroll 4
    for (int k = 0; k < 64; k += 4) {
      a0 = fmaf(Wc[(k + 0) * 64], cv[k + 0], a0);
      a1 = fmaf(Wc[(k + 1) * 64], cv[k + 1], a1);
      a2 = fmaf(Wc[(k + 2) * 64], cv[k + 2], a2);
      a3 = fmaf(Wc[(k + 3) * 64], cv[k + 3], a3);
    }
    scr[640 + c * 64 + j] = (a0 + a1) + (a2 + a3);
  }
  __syncthreads();

  if (tid < 64) {
    const float z1 = fmaxf(b1[tid] + scr[640 + tid] + scr[704 + tid] +
                           scr[768 + tid] + scr[832 + tid], 0.f);
    float p = z1 * w2[tid];
    for (int o = 32; o; o >>= 1) p += __shfl_xor(p, o);
    if (tid == 0) out[g] = 1.f / (1.f + expf(-(p + b2[0])));
  }
}

__global__ __launch_bounds__(256) void tl_reduce_kernel(const float* __restrict__ tl,
                                                        float* __restrict__ out) {
  __shared__ float s[256];
  float acc = 0.f;
  for (int i = threadIdx.x; i < BB; i += 256) acc += tl[i];
  s[threadIdx.x] = acc;
  __syncthreads();
  for (int off = 128; off > 0; off >>= 1) {
    if (threadIdx.x < off) s[threadIdx.x] += s[threadIdx.x + off];
    __syncthreads();
  }
  if (threadIdx.x == 0) out[BB] = s[0] * (1.f / (float)BB);
}

// ---------------------------------------------------------------------------
extern "C" void kernel_launch(void* const* d_in, const int* in_sizes, int n_in,
                              void* d_out, int out_size, void* d_ws, size_t ws_size,
                              hipStream_t stream) {
  const float* x        = (const float*)d_in[0];
  const float* edge_nrm = (const float*)d_in[1];
  const int*   src      = (const int*)d_in[2];
  const int*   dst      = (const int*)d_in[3];
  const int*   etype    = (const int*)d_in[4];
  // d_in[5] = graph_id: unused (contiguous 50-node graphs)
  const int*   ntype    = (const int*)d_in[6];
  const float* bases0   = (const float*)d_in[7];
  const float* coef0    = (const float*)d_in[8];
  const float* wself0   = (const float*)d_in[9];
  const float* bias0    = (const float*)d_in[10];
  const float* bases_r  = (const float*)d_in[11];
  const float* coef_r   = (const float*)d_in[12];
  const float* wself_r  = (const float*)d_in[13];
  const float* bias_r   = (const float*)d_in[14];
  const float* wp_u     = (const float*)d_in[15];
  const float* wt_u     = (const float*)d_in[16];
  const float* wp_i     = (const float*)d_in[17];
  const float* wt_i     = (const float*)d_in[18];
  const float* w1       = (const float*)d_in[19];
  const float* b1       = (const float*)d_in[20];
  const float* w2       = (const float*)d_in[21];
  const float* b2       = (const float*)d_in[22];
  float* out = (float*)d_out;

  // workspace layout (regions verified disjoint):
  //   hcat : N*128 f32 [0, N*512B)
  //          - head [0, 27.9MB) doubles as CSR 'staging' during the build
  //            (dead until aggregate_l0 writes hcat, which runs after pass2).
  //   R    : N*128 f32:
  //            Tb0 bf16 [0, N*256B) | hbA [N*256, N*320) | hbB [N*320, N*384)
  //   offs : ESLOTS int (padded slot space) | norms: ESLOTS bf16 |
  //   begs,ends: N each | gcursor: 256 | Wbuf: 69632 f32 |
  //   Whi/Wlo: 2*20480 bf16 | tl: B
  float*          hcat = (float*)d_ws;                       // N*128
  int2*           staging = (int2*)hcat;                     // CSR-build alias
  float*          R    = hcat + (size_t)NN * 128;            // N*128
  unsigned short* Tb0  = (unsigned short*)R;                 // N*128 bf16
  unsigned short* hbA  = Tb0 + (size_t)NN * 128;             // N*32 bf16
  unsigned short* hbB  = hbA + (size_t)NN * 32;              // N*32 bf16
  int*            offs = (int*)(R + (size_t)NN * 128);       // ESLOTS int
  unsigned short* norms= (unsigned short*)(offs + ESLOTS);   // ESLOTS bf16
  int*   begs    = (int*)(norms + ESLOTS);                   // N
  int*   ends    = begs + NN;                                // N
  int*   gcursor = ends + NN;                                // 256
  float* Wbuf    = (float*)(gcursor + 256);                  // 69632 f32
  unsigned short* Whi = (unsigned short*)(Wbuf + 69632);     // 20480 bf16
  unsigned short* Wlo = Whi + 20480;                         // 20480 bf16
  float* tl      = Wbuf + 69632 + 10240;                     // B

  size_t need = ((size_t)NN * 128 * 2 + ESLOTS + ESLOTS / 2 + 2 * NN +
                 256 + 69632 + 10240 + BB) * 4;
  if (ws_size < need) return;

  // --- weights (+gcursor init) + MFMA fragment packing ---
  wprep_kernel<<<(69632 + 255) / 256, 256, 0, stream>>>(
      bases0, coef0, wself0, bases_r, coef_r, wself_r,
      wp_u, wp_i, wt_u, wt_i, w1, Wbuf, gcursor);
  wprep2_kernel<<<80, 256, 0, stream>>>(Wbuf, Whi, Wlo);

  // --- CSR build (separate kernels: pass1 owns its 76.5KB LDS alone) ---
  pass1_kernel<<<EE / CHUNK, 256, 0, stream>>>(src, dst, etype, edge_nrm,
                                               gcursor, staging);
  pass2_kernel<<<NBUCK, 256, 0, stream>>>(staging, gcursor, begs, ends,
                                          offs, norms);

  // --- layer 0: MFMA transform (33KB LDS) + gather-aggregate ---
  transform_l0_kernel<<<NN / 64, 256, 0, stream>>>(x, Whi, Wlo, Tb0);
  aggregate_l0_kernel<<<NN / 32, 256, 0, stream>>>(Tb0, begs, ends, offs, norms,
                                                   bias0, hcat, hbA);

  // --- layers 1..3: fused gather + per-relation sums + MFMA + tanh ---
  agg_tf_kernel<<<NN / 32, 256, 0, stream>>>(
      hbA, begs, ends, offs, norms, Whi + 8192, Wlo + 8192, bias_r,
      hcat + 32, hbB);
  agg_tf_kernel<<<NN / 32, 256, 0, stream>>>(
      hbB, begs, ends, offs, norms, Whi + 12288, Wlo + 12288, bias_r + 32,
      hcat + 64, hbA);
  agg_tf_kernel<<<NN / 32, 256, 0, stream>>>(
      hbA, begs, ends, offs, norms, Whi + 16384, Wlo + 16384, bias_r + 64,
      hcat + 96, nullptr);

  // --- fused per-graph tail ---
  pool_head_kernel<<<BB, 256, 0, stream>>>(hcat, ntype,
                                           Wbuf + 20480, Wbuf + 53248,
                                           b1, w2, b2, out, tl);
  tl_reduce_kernel<<<1, 256, 0, stream>>>(tl, out);
}

// Round 17
// 581.437 us; speedup vs baseline: 1.0684x; 1.0405x over previous
//
#include <hip/hip_runtime.h>
#include <cstdint>
#include <cstddef>

// Problem constants (fixed by the reference).
#define NN   204800     // nodes
#define EE   3276800    // edges
#define BB   4096       // graphs
#define GS   50         // nodes per graph (contiguous blocks of 50)
#define NBUCK 200       // CSR sort buckets: 1024 nodes each
#define CHUNK 8192      // edges per pass1 block (400 blocks exactly)
#define BCAP  17408     // fixed bucket capacity: mean 16384 + >8 sigma
#define ESLOTS ((size_t)NBUCK * BCAP)   // padded edge-slot space (3,481,600)

typedef __attribute__((ext_vector_type(8))) short short8v;   // 8 bf16 (4 VGPR)
typedef __attribute__((ext_vector_type(4))) float f32x4;     // MFMA acc

__device__ __forceinline__ float bf2f(unsigned short u) {
  unsigned int x = ((unsigned int)u) << 16;
  return __int_as_float((int)x);
}
__device__ __forceinline__ unsigned short f2bf(float f) {
  unsigned int x = __float_as_uint(f);
  unsigned int r = (x + 0x7fffu + ((x >> 16) & 1u)) >> 16;   // RTN-even
  return (unsigned short)r;
}

// ---------------------------------------------------------------------------
// pass1: LDS counting-sort of an 8192-edge chunk by bucket (dst>>10),
// coalesced flush to fixed-capacity bucket regions in staging.
// ---------------------------------------------------------------------------
__global__ __launch_bounds__(256) void pass1_kernel(const int* __restrict__ src,
                                                    const int* __restrict__ dst,
                                                    const int* __restrict__ etype,
                                                    const float* __restrict__ en,
                                                    int* __restrict__ gcursor,
                                                    int2* __restrict__ staging) {
  __shared__ int2 stage[CHUNK];                 // 64 KB
  __shared__ unsigned char bid[CHUNK];          // 8 KB
  __shared__ int hist[NBUCK], cur[NBUCK], lo[NBUCK], gbase[NBUCK];
  __shared__ int sc[256];
  const int tid = threadIdx.x;
  const int ebase = blockIdx.x * CHUNK;

  for (int i = tid; i < NBUCK; i += 256) hist[i] = 0;
  __syncthreads();
  for (int i = tid; i < CHUNK; i += 256) {
    int bk = dst[ebase + i] >> 10;
    bid[i] = (unsigned char)bk;
    atomicAdd(&hist[bk], 1);
  }
  __syncthreads();
  int hv = (tid < NBUCK) ? hist[tid] : 0;
  sc[tid] = hv;
  __syncthreads();
  for (int off = 1; off < 256; off <<= 1) {
    int t = (tid >= off) ? sc[tid - off] : 0;
    __syncthreads();
    sc[tid] += t;
    __syncthreads();
  }
  if (tid < NBUCK) {
    int excl = sc[tid] - hv;
    lo[tid]  = excl;
    cur[tid] = excl;
    gbase[tid] = hv ? atomicAdd(&gcursor[tid], hv) : 0;
  }
  __syncthreads();
  for (int i = tid; i < CHUNK; i += 256) {
    int bk = bid[i];
    int p = atomicAdd(&cur[bk], 1);
    int s  = src[ebase + i];
    int et = etype[ebase + i];
    int d  = dst[ebase + i];
    int2 r;
    r.x = (s << 12) | (et << 10) | (d & 1023);
    r.y = __float_as_int(en[ebase + i]);
    stage[p] = r;
  }
  __syncthreads();
  const int wave = tid >> 6, lane = tid & 63;
  for (int bk = wave; bk < NBUCK; bk += 4) {
    const int len = hist[bk];
    const int l0  = lo[bk];
    const int gb  = gbase[bk];
    for (int i = lane; i < len; i += 64)
      staging[gb + i] = stage[l0 + i];
  }
}

// ---------------------------------------------------------------------------
// pass2: per-bucket node hist+scan -> begs/ends, L2-window scatter into the
// PADDED slot space [b*BCAP, b*BCAP+cnt): offs[] (src*256+et*64) + norms[] bf16.
// ---------------------------------------------------------------------------
__global__ __launch_bounds__(256) void pass2_kernel(const int2* __restrict__ staging,
                                                    const int* __restrict__ gcursor,
                                                    int* __restrict__ begs,
                                                    int* __restrict__ ends,
                                                    int* __restrict__ offs,
                                                    unsigned short* __restrict__ norms) {
  __shared__ int lhist[1024];
  __shared__ int lcur[1024];
  __shared__ int psum[256];
  const int b = blockIdx.x;
  const int tid = threadIdx.x;
  const int base = b * BCAP;
  const int cnt  = gcursor[b] - base;

  for (int i = tid; i < 1024; i += 256) lhist[i] = 0;
  __syncthreads();
  for (int i = tid; i < cnt; i += 256)
    atomicAdd(&lhist[staging[base + i].x & 1023], 1);
  __syncthreads();
  int s0 = lhist[4 * tid], s1 = lhist[4 * tid + 1];
  int s2 = lhist[4 * tid + 2], s3 = lhist[4 * tid + 3];
  int tot = s0 + s1 + s2 + s3;
  psum[tid] = tot;
  __syncthreads();
  for (int off = 1; off < 256; off <<= 1) {
    int t = (tid >= off) ? psum[tid - off] : 0;
    __syncthreads();
    psum[tid] += t;
    __syncthreads();
  }
  int o0 = base + psum[tid] - tot;
  int o1 = o0 + s0, o2 = o1 + s1, o3 = o2 + s2;
  const int nodeb = b * 1024;
  begs[nodeb + 4 * tid]     = o0;  ends[nodeb + 4 * tid]     = o1;  lcur[4 * tid]     = o0;
  begs[nodeb + 4 * tid + 1] = o1;  ends[nodeb + 4 * tid + 1] = o2;  lcur[4 * tid + 1] = o1;
  begs[nodeb + 4 * tid + 2] = o2;  ends[nodeb + 4 * tid + 2] = o3;  lcur[4 * tid + 2] = o2;
  begs[nodeb + 4 * tid + 3] = o3;  ends[nodeb + 4 * tid + 3] = o3 + s3;  lcur[4 * tid + 3] = o3;
  __syncthreads();
  for (int i = tid; i < cnt; i += 256) {
    int2 r = staging[base + i];
    int pos = atomicAdd(&lcur[r.x & 1023], 1);
    int s  = r.x >> 12;
    int et = (r.x >> 10) & 3;
    offs[pos]  = (s << 8) + (et << 6);          // src*256 + et*64
    norms[pos] = f2bf(__int_as_float(r.y));
  }
}

// ---------------------------------------------------------------------------
// Weight prep (+ gcursor init piggybacked on block 0):
//   Wcat0 [64,128] | WcatR[3][32,128] | Mt [2][128][128] = 0.125*wp@wt^T |
//   W1c [256][64] = Wp-block @ w1
// ---------------------------------------------------------------------------
__global__ __launch_bounds__(256) void wprep_kernel(
    const float* __restrict__ bases0, const float* __restrict__ coef0,
    const float* __restrict__ wself0,
    const float* __restrict__ bases_r, const float* __restrict__ coef_r,
    const float* __restrict__ wself_r,
    const float* __restrict__ wp_u, const float* __restrict__ wp_i,
    const float* __restrict__ wt_u, const float* __restrict__ wt_i,
    const float* __restrict__ w1,
    float* __restrict__ Wbuf, int* __restrict__ gcursor) {
  if (blockIdx.x == 0 && threadIdx.x < NBUCK)
    gcursor[threadIdx.x] = threadIdx.x * BCAP;
  int idx = blockIdx.x * 256 + threadIdx.x;
  if (idx < 8192) {                                      // Wcat0: [64][128]
    int i = idx >> 7, j = idx & 127;
    float v;
    if (j < 96) {
      int r = j >> 5, f = j & 31;
      v = coef0[r * 2 + 0] * bases0[0 * 2048 + i * 32 + f]
        + coef0[r * 2 + 1] * bases0[1 * 2048 + i * 32 + f];
    } else {
      v = wself0[i * 32 + (j - 96)];
    }
    Wbuf[idx] = v;
    return;
  }
  int idx2 = idx - 8192;
  if (idx2 < 3 * 4096) {                                 // WcatR[l]: [32][128]
    int l = idx2 >> 12, rem = idx2 & 4095;
    int i = rem >> 7, j = rem & 127;
    float v;
    if (j < 96) {
      int r = j >> 5, f = j & 31;
      v = coef_r[l * 6 + r * 2 + 0] * bases_r[l * 2048 + 0 * 1024 + i * 32 + f]
        + coef_r[l * 6 + r * 2 + 1] * bases_r[l * 2048 + 1 * 1024 + i * 32 + f];
    } else {
      v = wself_r[l * 1024 + i * 32 + (j - 96)];
    }
    Wbuf[idx] = v;
    return;
  }
  int idx3 = idx2 - 12288;
  if (idx3 < 32768) {                                    // Mt[side][kk][k]
    int side = idx3 >> 14;
    int r = idx3 & 16383;
    int kk = r >> 7, k = r & 127;
    const float* wp = side ? wp_i : wp_u;
    const float* wt = side ? wt_i : wt_u;
    float acc = 0.f;
#pragma unroll 8
    for (int j = 0; j < 64; ++j)
      acc = fmaf(wp[k * 64 + j], wt[kk * 64 + j], acc);
    Wbuf[idx] = acc * 0.125f;                            // /sqrt(PH) folded
    return;
  }
  int idx4 = idx3 - 32768;
  if (idx4 < 16384) {                                    // W1c[k'][t]
    int kp = idx4 >> 6, t = idx4 & 63;
    int side = kp >> 7, k = kp & 127;
    const float* wp = side ? wp_i : wp_u;
    float acc = 0.f;
#pragma unroll 8
    for (int j = 0; j < 64; ++j)
      acc = fmaf(wp[k * 64 + j], w1[(side * 64 + j) * 64 + t], acc);
    Wbuf[idx] = acc;
  }
}

// wprep2: MFMA B-fragments, bf16 hi + residual lo (layouts as round 11).
__global__ __launch_bounds__(256) void wprep2_kernel(const float* __restrict__ Wbuf,
                                                     unsigned short* __restrict__ Whi,
                                                     unsigned short* __restrict__ Wlo) {
  int e = blockIdx.x * 256 + threadIdx.x;
  if (e >= 20480) return;
  float v;
  if (e < 8192) {                    // layer 0, K=64, 128 out cols
    int j = e & 7, l = (e >> 3) & 63, c = (e >> 9) & 7, q = e >> 12;
    int k   = q * 32 + (l >> 4) * 8 + j;
    int col = c * 16 + (l & 15);
    v = Wbuf[k * 128 + col];
  } else {                           // layers 1-3, K=128, 32 out cols
    int e2 = e - 8192;
    int lay = e2 >> 12, r = e2 & 4095;
    int j = r & 7, l = (r >> 3) & 63, qc = r >> 9;       // 0..7
    int q = qc >> 1, c = qc & 1;
    int k = q * 32 + (l >> 4) * 8 + j;                   // 0..127
    int o = c * 16 + (l & 15);                           // 0..31
    const float* Wc = Wbuf + 8192 + lay * 4096;          // WcatR[lay][32][128]
    v = (k < 96) ? Wc[(k & 31) * 128 + (k >> 5) * 32 + o]
                 : Wc[(k - 96) * 128 + 96 + o];
  }
  unsigned short hi = f2bf(v);
  Whi[e] = hi;
  Wlo[e] = f2bf(v - bf2f(hi));
}

// ---------------------------------------------------------------------------
// Layer-0 MFMA transform: x[N,64] (f32, hi/lo split in-register) @
// Wcat0[64,128] -> Tb0 [N][128] bf16 (msgs [0,96), self [96,128)).
// ---------------------------------------------------------------------------
__global__ __launch_bounds__(256) void transform_l0_kernel(
    const float* __restrict__ x,
    const unsigned short* __restrict__ Whi, const unsigned short* __restrict__ Wlo,
    unsigned short* __restrict__ Tb0) {
  __shared__ float C[64][129];
  const int tid = threadIdx.x;
  const int wv = tid >> 6, l = tid & 63;
  const int l15 = l & 15, kg = l >> 4;
  const int row = blockIdx.x * 64 + wv * 16 + l15;

  short8v ah[2], al[2];
#pragma unroll
  for (int q = 0; q < 2; ++q) {
    const float* xp = x + (size_t)row * 64 + q * 32 + kg * 8;
    const float4 v0 = *reinterpret_cast<const float4*>(xp);
    const float4 v1 = *reinterpret_cast<const float4*>(xp + 4);
    const float vv[8] = {v0.x, v0.y, v0.z, v0.w, v1.x, v1.y, v1.z, v1.w};
#pragma unroll
    for (int f = 0; f < 8; ++f) {
      const unsigned short h = f2bf(vv[f]);
      ah[q][f] = (short)h;
      al[q][f] = (short)f2bf(vv[f] - bf2f(h));
    }
  }

#pragma unroll
  for (int c = 0; c < 8; ++c) {
    f32x4 a = {0.f, 0.f, 0.f, 0.f};
#pragma unroll
    for (int q = 0; q < 2; ++q) {
      const size_t fb = ((size_t)(q * 8 + c) * 64 + l) * 8;
      const short8v bh = *reinterpret_cast<const short8v*>(Whi + fb);
      const short8v bl = *reinterpret_cast<const short8v*>(Wlo + fb);
      a = __builtin_amdgcn_mfma_f32_16x16x32_bf16(ah[q], bh, a, 0, 0, 0);
      a = __builtin_amdgcn_mfma_f32_16x16x32_bf16(al[q], bh, a, 0, 0, 0);
      a = __builtin_amdgcn_mfma_f32_16x16x32_bf16(ah[q], bl, a, 0, 0, 0);
    }
    // C/D layout [verified]: col = lane&15, row_in_tile = (lane>>4)*4 + reg
#pragma unroll
    for (int r = 0; r < 4; ++r)
      C[wv * 16 + kg * 4 + r][c * 16 + l15] = a[r];
  }
  __syncthreads();

  const int row64 = tid & 63, q = tid >> 6;
  const int node = blockIdx.x * 64 + row64;
#pragma unroll
  for (int v = 0; v < 4; ++v) {
    const int cb = q * 32 + v * 8;
    uint4 pk;
    pk.x = (unsigned)f2bf(C[row64][cb + 0]) | ((unsigned)f2bf(C[row64][cb + 1]) << 16);
    pk.y = (unsigned)f2bf(C[row64][cb + 2]) | ((unsigned)f2bf(C[row64][cb + 3]) << 16);
    pk.z = (unsigned)f2bf(C[row64][cb + 4]) | ((unsigned)f2bf(C[row64][cb + 5]) << 16);
    pk.w = (unsigned)f2bf(C[row64][cb + 6]) | ((unsigned)f2bf(C[row64][cb + 7]) << 16);
    *reinterpret_cast<uint4*>(Tb0 + (size_t)node * 128 + cb) = pk;
  }
}

// ---------------------------------------------------------------------------
// Layer-0 aggregate: gathers pre-transformed messages from Tb0 (64B/edge),
// adds bf16 self (row bytes [192,256)) + bias, tanh -> hcat slot0 + hbA.
// offs/norms via plain cached loads (8 lanes/node read the SAME values —
// L1/L2 broadcast absorbs redundancy; nt loads made it 8x HBM, round 16).
// ---------------------------------------------------------------------------
__global__ __launch_bounds__(256) void aggregate_l0_kernel(
    const unsigned short* __restrict__ Tb0,
    const int* __restrict__ begs, const int* __restrict__ ends,
    const int* __restrict__ offs, const unsigned short* __restrict__ norms,
    const float* __restrict__ bias,
    float* __restrict__ hcat, unsigned short* __restrict__ hbA) {
  const int node = blockIdx.x * 32 + (threadIdx.x >> 3);
  const int f4   = (threadIdx.x & 7) * 4;
  const int loff = f4 * 2;
  const char* Tbc = (const char*)Tb0;
  const int beg = begs[node];
  const int end = ends[node];
  const ushort4 sb = *reinterpret_cast<const ushort4*>(Tbc + (size_t)node * 256 + 192 + loff);
  const float4 bv  = *reinterpret_cast<const float4*>(&bias[f4]);
  float ax = bf2f(sb.x) + bv.x, ay = bf2f(sb.y) + bv.y;
  float az = bf2f(sb.z) + bv.z, aw = bf2f(sb.w) + bv.w;

  int k = beg;
  for (; k + 8 <= end; k += 8) {
    int od[8]; unsigned short nb[8];
#pragma unroll
    for (int u = 0; u < 8; ++u) od[u] = offs[k + u];
#pragma unroll
    for (int u = 0; u < 8; ++u) nb[u] = norms[k + u];
    ushort4 mv[8];
#pragma unroll
    for (int u = 0; u < 8; ++u)
      mv[u] = *reinterpret_cast<const ushort4*>(Tbc + od[u] + loff);
#pragma unroll
    for (int u = 0; u < 8; ++u) {
      const float nm = bf2f(nb[u]);
      ax = fmaf(bf2f(mv[u].x), nm, ax);
      ay = fmaf(bf2f(mv[u].y), nm, ay);
      az = fmaf(bf2f(mv[u].z), nm, az);
      aw = fmaf(bf2f(mv[u].w), nm, aw);
    }
  }
  for (; k < end; ++k) {
    const int od = offs[k];
    const float nm = bf2f(norms[k]);
    ushort4 m0 = *reinterpret_cast<const ushort4*>(Tbc + od + loff);
    ax = fmaf(bf2f(m0.x), nm, ax);
    ay = fmaf(bf2f(m0.y), nm, ay);
    az = fmaf(bf2f(m0.z), nm, az);
    aw = fmaf(bf2f(m0.w), nm, aw);
  }
  float4 o;
  o.x = tanhf(ax); o.y = tanhf(ay); o.z = tanhf(az); o.w = tanhf(aw);
  *reinterpret_cast<float4*>(&hcat[(size_t)node * 128 + f4]) = o;
  ushort4 h;
  h.x = f2bf(o.x); h.y = f2bf(o.y); h.z = f2bf(o.z); h.w = f2bf(o.w);
  *reinterpret_cast<ushort4*>(hbA + (size_t)node * 32 + f4) = h;
}

// ---------------------------------------------------------------------------
// FUSED layers 1-3: 32 nodes/block, 8 lanes/node gather from compact
// hbX [N][32]b; per-relation sums -> LDS bf16 [32][136]; MFMA [128->32]
// (W hi/lo); tanh+bias -> hcat slot (+ next hbY). Plain cached stream loads.
// ---------------------------------------------------------------------------
__global__ __launch_bounds__(256, 8) void agg_tf_kernel(
    const unsigned short* __restrict__ hbX,
    const int* __restrict__ begs, const int* __restrict__ ends,
    const int* __restrict__ offs, const unsigned short* __restrict__ norms,
    const unsigned short* __restrict__ Whi, const unsigned short* __restrict__ Wlo,
    const float* __restrict__ bias,
    float* __restrict__ hcatSlot, unsigned short* __restrict__ hbY) {
  __shared__ __align__(16) unsigned short sld[32][136];
  __shared__ float C[32][33];
  const int tid = threadIdx.x;

  // ---- phase A: 8 lanes/node, 4 features (8B) each ----
  {
    const int nl   = tid >> 3;                 // 0..31
    const int node = blockIdx.x * 32 + nl;
    const int f4   = (tid & 7) * 4;
    const int loff = f4 * 2;
    const char* hbc = (const char*)hbX;
    const int beg = begs[node], end = ends[node];
    float a0x = 0.f, a0y = 0.f, a0z = 0.f, a0w = 0.f;
    float a1x = 0.f, a1y = 0.f, a1z = 0.f, a1w = 0.f;
    float a2x = 0.f, a2y = 0.f, a2z = 0.f, a2w = 0.f;

    int k = beg;
    for (; k + 8 <= end; k += 8) {
      int od[8]; unsigned short nb[8];
#pragma unroll
      for (int u = 0; u < 8; ++u) od[u] = offs[k + u];
#pragma unroll
      for (int u = 0; u < 8; ++u) nb[u] = norms[k + u];
      ushort4 mv[8];
#pragma unroll
      for (int u = 0; u < 8; ++u)
        mv[u] = *reinterpret_cast<const ushort4*>(hbc + ((od[u] >> 2) & ~63) + loff);
#pragma unroll
      for (int u = 0; u < 8; ++u) {
        const int et = (od[u] >> 6) & 3;
        const float nm = bf2f(nb[u]);
        const float n0 = (et == 0) ? nm : 0.f;
        const float n1 = (et == 1) ? nm : 0.f;
        const float n2 = (et == 2) ? nm : 0.f;
        const float vx = bf2f(mv[u].x), vy = bf2f(mv[u].y);
        const float vz = bf2f(mv[u].z), vw = bf2f(mv[u].w);
        a0x = fmaf(vx, n0, a0x); a0y = fmaf(vy, n0, a0y);
        a0z = fmaf(vz, n0, a0z); a0w = fmaf(vw, n0, a0w);
        a1x = fmaf(vx, n1, a1x); a1y = fmaf(vy, n1, a1y);
        a1z = fmaf(vz, n1, a1z); a1w = fmaf(vw, n1, a1w);
        a2x = fmaf(vx, n2, a2x); a2y = fmaf(vy, n2, a2y);
        a2z = fmaf(vz, n2, a2z); a2w = fmaf(vw, n2, a2w);
      }
    }
    for (; k < end; ++k) {
      const int od = offs[k];
      const int et = (od >> 6) & 3;
      const float nm = bf2f(norms[k]);
      const float n0 = (et == 0) ? nm : 0.f;
      const float n1 = (et == 1) ? nm : 0.f;
      const float n2 = (et == 2) ? nm : 0.f;
      ushort4 m0 = *reinterpret_cast<const ushort4*>(hbc + ((od >> 2) & ~63) + loff);
      const float vx = bf2f(m0.x), vy = bf2f(m0.y), vz = bf2f(m0.z), vw = bf2f(m0.w);
      a0x = fmaf(vx, n0, a0x); a0y = fmaf(vy, n0, a0y);
      a0z = fmaf(vz, n0, a0z); a0w = fmaf(vw, n0, a0w);
      a1x = fmaf(vx, n1, a1x); a1y = fmaf(vy, n1, a1y);
      a1z = fmaf(vz, n1, a1z); a1w = fmaf(vw, n1, a1w);
      a2x = fmaf(vx, n2, a2x); a2y = fmaf(vy, n2, a2y);
      a2z = fmaf(vz, n2, a2z); a2w = fmaf(vw, n2, a2w);
    }
    ushort4 s0, s1, s2;
    s0.x = f2bf(a0x); s0.y = f2bf(a0y); s0.z = f2bf(a0z); s0.w = f2bf(a0w);
    s1.x = f2bf(a1x); s1.y = f2bf(a1y); s1.z = f2bf(a1z); s1.w = f2bf(a1w);
    s2.x = f2bf(a2x); s2.y = f2bf(a2y); s2.z = f2bf(a2z); s2.w = f2bf(a2w);
    *reinterpret_cast<ushort4*>(&sld[nl][f4])      = s0;
    *reinterpret_cast<ushort4*>(&sld[nl][32 + f4]) = s1;
    *reinterpret_cast<ushort4*>(&sld[nl][64 + f4]) = s2;
    *reinterpret_cast<ushort4*>(&sld[nl][96 + f4]) =
        *reinterpret_cast<const ushort4*>(hbX + (size_t)node * 32 + f4);
  }
  __syncthreads();

  // ---- phase B: 4 waves, wave w -> (row-half w&1, c-tile w>>1) ----
  {
    const int w = tid >> 6, l = tid & 63;
    const int rg = w & 1, c = w >> 1;
    const int l15 = l & 15, kg = l >> 4;
    const int row = rg * 16 + l15;
    short8v af[4];
#pragma unroll
    for (int q = 0; q < 4; ++q)
      af[q] = *reinterpret_cast<const short8v*>(&sld[row][q * 32 + kg * 8]);
    f32x4 a = {0.f, 0.f, 0.f, 0.f};
#pragma unroll
    for (int q = 0; q < 4; ++q) {
      const size_t fb = ((size_t)(q * 2 + c) * 64 + l) * 8;
      const short8v bh = *reinterpret_cast<const short8v*>(Whi + fb);
      const short8v bl = *reinterpret_cast<const short8v*>(Wlo + fb);
      a = __builtin_amdgcn_mfma_f32_16x16x32_bf16(af[q], bh, a, 0, 0, 0);
      a = __builtin_amdgcn_mfma_f32_16x16x32_bf16(af[q], bl, a, 0, 0, 0);
    }
    // C/D layout [verified]: col = lane&15, row_in_tile = (lane>>4)*4 + reg
#pragma unroll
    for (int r = 0; r < 4; ++r)
      C[rg * 16 + kg * 4 + r][c * 16 + l15] = a[r];
  }
  __syncthreads();

  // ---- epilogue: tanh + bias -> hcat slot (+ next hb) ----
  {
    const int row32 = tid & 31, g = tid >> 5;  // g: 4-col group 0..7
    const int node = blockIdx.x * 32 + row32;
    float z[4];
#pragma unroll
    for (int v = 0; v < 4; ++v)
      z[v] = tanhf(C[row32][g * 4 + v] + bias[g * 4 + v]);
    float4 f0 = {z[0], z[1], z[2], z[3]};
    *reinterpret_cast<float4*>(hcatSlot + (size_t)node * 128 + g * 4) = f0;
    if (hbY) {
      ushort4 pk;
      pk.x = f2bf(z[0]); pk.y = f2bf(z[1]); pk.z = f2bf(z[2]); pk.w = f2bf(z[3]);
      *reinterpret_cast<ushort4*>(hbY + (size_t)node * 32 + g * 4) = pk;
    }
  }
}

// ---------------------------------------------------------------------------
// Fused per-graph tail (unchanged; XCD-chunked graph swizzle).
// ---------------------------------------------------------------------------
__global__ __launch_bounds__(256) void pool_head_kernel(
    const float* __restrict__ hcat, const int* __restrict__ ntype,
    const float* __restrict__ Mt,   // [2][128][128], 0.125 folded
    const float* __restrict__ W1c,  // [256][64]
    const float* __restrict__ b1,
    const float* __restrict__ w2, const float* __restrict__ b2,
    float* __restrict__ out, float* __restrict__ tl) {
  __shared__ float hl[GS * 129];
  __shared__ float scr[1024];
  __shared__ float av2[256];
  __shared__ float red[4];
  __shared__ float cnts[4];
  __shared__ int   snt[64];
  __shared__ int   sntp[64];

  const int g    = (blockIdx.x & 7) * (BB / 8) + (blockIdx.x >> 3);  // XCD chunk
  const int gp   = (g + BB - 1) & (BB - 1);
  const int tid  = threadIdx.x;
  const int lane = tid & 63;

  const float* hg  = hcat + (size_t)g  * (GS * 128);
  const float* hp  = hcat + (size_t)gp * (GS * 128);
  const int*   ntg = ntype + g  * GS;
  const int*   ntp = ntype + gp * GS;

  if (tid < 64) {
    snt[tid] = (tid < GS) ? ntg[tid] : 99;
    unsigned long long bu = __ballot(snt[tid] == 0);
    unsigned long long bi = __ballot(snt[tid] == 1);
    if (lane == 0) {
      cnts[0] = 1.f / ((float)__popcll(bu) + 1e-8f);
      cnts[1] = 1.f / ((float)__popcll(bi) + 1e-8f);
    }
  } else if (tid < 128) {
    sntp[lane] = (lane < GS) ? ntp[lane] : 99;
    unsigned long long bp = __ballot(sntp[lane] == 1);
    if (lane == 0) cnts[2] = 1.f / ((float)__popcll(bp) + 1e-8f);
  }

  {
    const int rowg = tid >> 5;
    const int kq   = (tid & 31) * 4;
    float spx = 0.f, spy = 0.f, spz = 0.f, spw = 0.f;
#pragma unroll
    for (int p = 0; p < 7; ++p) {
      const int r = rowg + 8 * p;
      if (r < GS) {
        const float4 v = *reinterpret_cast<const float4*>(hg + r * 128 + kq);
        hl[r * 129 + kq + 0] = v.x;
        hl[r * 129 + kq + 1] = v.y;
        hl[r * 129 + kq + 2] = v.z;
        hl[r * 129 + kq + 3] = v.w;
        if (ntp[r] == 1) {
          const float4 w = *reinterpret_cast<const float4*>(hp + r * 128 + kq);
          spx += w.x; spy += w.y; spz += w.z; spw += w.w;
        }
      }
    }
    scr[rowg * 128 + kq + 0] = spx;
    scr[rowg * 128 + kq + 1] = spy;
    scr[rowg * 128 + kq + 2] = spz;
    scr[rowg * 128 + kq + 3] = spw;
  }
  __syncthreads();

  if (tid < 128) {
    const int kf = tid;
    float su = 0.f, si = 0.f;
#pragma unroll
    for (int r = 0; r < GS; ++r) {
      const float v = hl[r * 129 + kf];
      if (snt[r] == 0) su += v; else si += v;
    }
    float sp = 0.f;
#pragma unroll
    for (int rg = 0; rg < 8; ++rg) sp += scr[rg * 128 + kf];
    const float auk = su * cnts[0];
    const float aik = si * cnts[1];
    const float apk = sp * cnts[2];
    av2[kf]       = auk;
    av2[128 + kf] = aik;
    float d1 = (auk - aik) * (auk - aik);
    float d2 = (auk - apk) * (auk - apk);
    for (int o = 32; o; o >>= 1) {
      d1 += __shfl_xor(d1, o);
      d2 += __shfl_xor(d2, o);
    }
    if (lane == 0) { red[tid >> 6] = d1; red[2 + (tid >> 6)] = d2; }
  }
  __syncthreads();

  {
    const int side = tid >> 7, kf = tid & 127;
    const float* M  = Mt + (size_t)side * 16384 + kf;
    const float* av = av2 + side * 128;
    float a0 = 0.f, a1 = 0.f, a2 = 0.f, a3 = 0.f;
#pragma unroll 4
    for (int kk = 0; kk < 128; kk += 4) {
      a0 = fmaf(M[(kk + 0) * 128], av[kk + 0], a0);
      a1 = fmaf(M[(kk + 1) * 128], av[kk + 1], a1);
      a2 = fmaf(M[(kk + 2) * 128], av[kk + 2], a2);
      a3 = fmaf(M[(kk + 3) * 128], av[kk + 3], a3);
    }
    scr[tid] = (a0 + a1) + (a2 + a3);
  }
  if (tid == 0) tl[g] = fmaxf(0.f, (red[0] + red[1]) - (red[2] + red[3]) + 1.0f);
  __syncthreads();

  if (tid < 128) {
    const int side = tid >> 6;
    const float* q = scr + side * 128;
    float v = -1e9f;
    bool msk = false;
    if (lane < GS) {
      msk = (snt[lane] == side);
      float a0 = 0.f, a1 = 0.f;
#pragma unroll 8
      for (int k = 0; k < 128; k += 2) {
        a0 = fmaf(hl[lane * 129 + k], q[k], a0);
        a1 = fmaf(hl[lane * 129 + k + 1], q[k + 1], a1);
      }
      v = msk ? (a0 + a1) : -1e9f;
    }
    float m = v;
    for (int o = 32; o; o >>= 1) m = fmaxf(m, __shfl_xor(m, o));
    float e = (lane < GS && msk) ? expf(v - m) : 0.f;
    float z = e;
    for (int o = 32; o; o >>= 1) z += __shfl_xor(z, o);
    const float invz = 1.f / (z + 1e-8f);
    if (lane < GS) scr[256 + side * 64 + lane] = e * invz;
  }
  __syncthreads();

  {
    const int side = tid >> 7, kf = tid & 127;
    const float* a = scr + 256 + side * 64;
    float acc = 0.f;
#pragma unroll
    for (int nl = 0; nl < GS; ++nl)
      acc = fmaf(a[nl], hl[nl * 129 + kf], acc);
    scr[384 + side * 128 + kf] = acc;
  }
  __syncthreads();

  {
    const int j = tid & 63, c = tid >> 6;
    const float* Wc = W1c + (size_t)c * 64 * 64 + j;
    const float* cv = scr + 384 + c * 64;
    float a0 = 0.f, a1 = 0.f, a2 = 0.f, a3 = 0.f;
#pragma unroll 4
    for (int k = 0; k < 64; k += 4) {
      a0 = fmaf(Wc[(k + 0) * 64], cv[k + 0], a0);
      a1 = fmaf(Wc[(k + 1) * 64], cv[k + 1], a1);
      a2 = fmaf(Wc[(k + 2) * 64], cv[k + 2], a2);
      a3 = fmaf(Wc[(k + 3) * 64], cv[k + 3], a3);
    }
    scr[640 + c * 64 + j] = (a0 + a1) + (a2 + a3);
  }
  __syncthreads();

  if (tid < 64) {
    const float z1 = fmaxf(b1[tid] + scr[640 + tid] + scr[704 + tid] +
                           scr[768 + tid] + scr[832 + tid], 0.f);
    float p = z1 * w2[tid];
    for (int o = 32; o; o >>= 1) p += __shfl_xor(p, o);
    if (tid == 0) out[g] = 1.f / (1.f + expf(-(p + b2[0])));
  }
}

__global__ __launch_bounds__(256) void tl_reduce_kernel(const float* __restrict__ tl,
                                                        float* __restrict__ out) {
  __shared__ float s[256];
  float acc = 0.f;
  for (int i = threadIdx.x; i < BB; i += 256) acc += tl[i];
  s[threadIdx.x] = acc;
  __syncthreads();
  for (int off = 128; off > 0; off >>= 1) {
    if (threadIdx.x < off) s[threadIdx.x] += s[threadIdx.x + off];
    __syncthreads();
  }
  if (threadIdx.x == 0) out[BB] = s[0] * (1.f / (float)BB);
}

// ---------------------------------------------------------------------------
extern "C" void kernel_launch(void* const* d_in, const int* in_sizes, int n_in,
                              void* d_out, int out_size, void* d_ws, size_t ws_size,
                              hipStream_t stream) {
  const float* x        = (const float*)d_in[0];
  const float* edge_nrm = (const float*)d_in[1];
  const int*   src      = (const int*)d_in[2];
  const int*   dst      = (const int*)d_in[3];
  const int*   etype    = (const int*)d_in[4];
  // d_in[5] = graph_id: unused (contiguous 50-node graphs)
  const int*   ntype    = (const int*)d_in[6];
  const float* bases0   = (const float*)d_in[7];
  const float* coef0    = (const float*)d_in[8];
  const float* wself0   = (const float*)d_in[9];
  const float* bias0    = (const float*)d_in[10];
  const float* bases_r  = (const float*)d_in[11];
  const float* coef_r   = (const float*)d_in[12];
  const float* wself_r  = (const float*)d_in[13];
  const float* bias_r   = (const float*)d_in[14];
  const float* wp_u     = (const float*)d_in[15];
  const float* wt_u     = (const float*)d_in[16];
  const float* wp_i     = (const float*)d_in[17];
  const float* wt_i     = (const float*)d_in[18];
  const float* w1       = (const float*)d_in[19];
  const float* b1       = (const float*)d_in[20];
  const float* w2       = (const float*)d_in[21];
  const float* b2       = (const float*)d_in[22];
  float* out = (float*)d_out;

  // workspace layout (regions verified disjoint):
  //   hcat : N*128 f32 [0, N*512B); head doubles as CSR 'staging' (dead
  //          until aggregate_l0 writes hcat, which runs after pass2).
  //   R    : Tb0 bf16 [0, N*256B) | hbA [N*256, N*320) | hbB [N*320, N*384)
  //   offs : ESLOTS int | norms: ESLOTS bf16 | begs,ends: N each |
  //   gcursor: 256 | Wbuf: 69632 f32 | Whi/Wlo: 2*20480 bf16 | tl: B
  float*          hcat = (float*)d_ws;                       // N*128
  int2*           staging = (int2*)hcat;                     // CSR-build alias
  float*          R    = hcat + (size_t)NN * 128;            // N*128
  unsigned short* Tb0  = (unsigned short*)R;                 // N*128 bf16
  unsigned short* hbA  = Tb0 + (size_t)NN * 128;             // N*32 bf16
  unsigned short* hbB  = hbA + (size_t)NN * 32;              // N*32 bf16
  int*            offs = (int*)(R + (size_t)NN * 128);       // ESLOTS int
  unsigned short* norms= (unsigned short*)(offs + ESLOTS);   // ESLOTS bf16
  int*   begs    = (int*)(norms + ESLOTS);                   // N
  int*   ends    = begs + NN;                                // N
  int*   gcursor = ends + NN;                                // 256
  float* Wbuf    = (float*)(gcursor + 256);                  // 69632 f32
  unsigned short* Whi = (unsigned short*)(Wbuf + 69632);     // 20480 bf16
  unsigned short* Wlo = Whi + 20480;                         // 20480 bf16
  float* tl      = Wbuf + 69632 + 10240;                     // B

  size_t need = ((size_t)NN * 128 * 2 + ESLOTS + ESLOTS / 2 + 2 * NN +
                 256 + 69632 + 10240 + BB) * 4;
  if (ws_size < need) return;

  // --- weights (+gcursor init) + MFMA fragment packing ---
  wprep_kernel<<<(69632 + 255) / 256, 256, 0, stream>>>(
      bases0, coef0, wself0, bases_r, coef_r, wself_r,
      wp_u, wp_i, wt_u, wt_i, w1, Wbuf, gcursor);
  wprep2_kernel<<<80, 256, 0, stream>>>(Wbuf, Whi, Wlo);

  // --- CSR build ---
  pass1_kernel<<<EE / CHUNK, 256, 0, stream>>>(src, dst, etype, edge_nrm,
                                               gcursor, staging);
  pass2_kernel<<<NBUCK, 256, 0, stream>>>(staging, gcursor, begs, ends,
                                          offs, norms);

  // --- layer 0: MFMA transform + gather-aggregate ---
  transform_l0_kernel<<<NN / 64, 256, 0, stream>>>(x, Whi, Wlo, Tb0);
  aggregate_l0_kernel<<<NN / 32, 256, 0, stream>>>(Tb0, begs, ends, offs, norms,
                                                   bias0, hcat, hbA);

  // --- layers 1..3: fused gather + per-relation sums + MFMA + tanh ---
  agg_tf_kernel<<<NN / 32, 256, 0, stream>>>(
      hbA, begs, ends, offs, norms, Whi + 8192, Wlo + 8192, bias_r,
      hcat + 32, hbB);
  agg_tf_kernel<<<NN / 32, 256, 0, stream>>>(
      hbB, begs, ends, offs, norms, Whi + 12288, Wlo + 12288, bias_r + 32,
      hcat + 64, hbA);
  agg_tf_kernel<<<NN / 32, 256, 0, stream>>>(
      hbA, begs, ends, offs, norms, Whi + 16384, Wlo + 16384, bias_r + 64,
      hcat + 96, nullptr);

  // --- fused per-graph tail ---
  pool_head_kernel<<<BB, 256, 0, stream>>>(hcat, ntype,
                                           Wbuf + 20480, Wbuf + 53248,
                                           b1, w2, b2, out, tl);
  tl_reduce_kernel<<<1, 256, 0, stream>>>(tl, out);
}

// Round 18
// 501.483 us; speedup vs baseline: 1.2388x; 1.1594x over previous
//
#include <hip/hip_runtime.h>
#include <cstdint>
#include <cstddef>

// Problem constants (fixed by the reference).
#define NN   204800     // nodes
#define EE   3276800    // edges
#define BB   4096       // graphs
#define GS   50         // nodes per graph (contiguous blocks of 50)
#define NBUCK 200       // CSR sort buckets: 1024 nodes each
#define CHUNK 8192      // edges per pass1 block (400 blocks exactly)
#define BCAP  17408     // fixed bucket capacity: mean 16384 + >8 sigma
#define ESLOTS ((size_t)NBUCK * BCAP)   // padded edge-slot space (3,481,600)

typedef __attribute__((ext_vector_type(8))) short short8v;   // 8 bf16 (4 VGPR)
typedef __attribute__((ext_vector_type(4))) float f32x4;     // MFMA acc

__device__ __forceinline__ float bf2f(unsigned short u) {
  unsigned int x = ((unsigned int)u) << 16;
  return __int_as_float((int)x);
}
__device__ __forceinline__ unsigned short f2bf(float f) {
  unsigned int x = __float_as_uint(f);
  unsigned int r = (x + 0x7fffu + ((x >> 16) & 1u)) >> 16;   // RTN-even
  return (unsigned short)r;
}

// ---------------------------------------------------------------------------
// pass1: LDS counting-sort of an 8192-edge chunk by bucket (dst>>10),
// coalesced flush to fixed-capacity bucket regions in staging.
// ---------------------------------------------------------------------------
__global__ __launch_bounds__(256) void pass1_kernel(const int* __restrict__ src,
                                                    const int* __restrict__ dst,
                                                    const int* __restrict__ etype,
                                                    const float* __restrict__ en,
                                                    int* __restrict__ gcursor,
                                                    int2* __restrict__ staging) {
  __shared__ int2 stage[CHUNK];                 // 64 KB
  __shared__ unsigned char bid[CHUNK];          // 8 KB
  __shared__ int hist[NBUCK], cur[NBUCK], lo[NBUCK], gbase[NBUCK];
  __shared__ int sc[256];
  const int tid = threadIdx.x;
  const int ebase = blockIdx.x * CHUNK;

  for (int i = tid; i < NBUCK; i += 256) hist[i] = 0;
  __syncthreads();
  for (int i = tid; i < CHUNK; i += 256) {
    int bk = dst[ebase + i] >> 10;
    bid[i] = (unsigned char)bk;
    atomicAdd(&hist[bk], 1);
  }
  __syncthreads();
  int hv = (tid < NBUCK) ? hist[tid] : 0;
  sc[tid] = hv;
  __syncthreads();
  for (int off = 1; off < 256; off <<= 1) {
    int t = (tid >= off) ? sc[tid - off] : 0;
    __syncthreads();
    sc[tid] += t;
    __syncthreads();
  }
  if (tid < NBUCK) {
    int excl = sc[tid] - hv;
    lo[tid]  = excl;
    cur[tid] = excl;
    gbase[tid] = hv ? atomicAdd(&gcursor[tid], hv) : 0;
  }
  __syncthreads();
  for (int i = tid; i < CHUNK; i += 256) {
    int bk = bid[i];
    int p = atomicAdd(&cur[bk], 1);
    int s  = src[ebase + i];
    int et = etype[ebase + i];
    int d  = dst[ebase + i];
    int2 r;
    r.x = (s << 12) | (et << 10) | (d & 1023);
    r.y = __float_as_int(en[ebase + i]);
    stage[p] = r;
  }
  __syncthreads();
  const int wave = tid >> 6, lane = tid & 63;
  for (int bk = wave; bk < NBUCK; bk += 4) {
    const int len = hist[bk];
    const int l0  = lo[bk];
    const int gb  = gbase[bk];
    for (int i = lane; i < len; i += 64)
      staging[gb + i] = stage[l0 + i];
  }
}

// ---------------------------------------------------------------------------
// pass2: per-bucket node hist+scan -> begs/ends, L2-window scatter into the
// PADDED slot space [b*BCAP, b*BCAP+cnt) -> edata int2 {src*256+et*64, normf32}.
// (int2 format: single 8B store/load per edge — the offs/norms split of r17
//  doubled stream instruction count and lost; reverted.)
// ---------------------------------------------------------------------------
__global__ __launch_bounds__(256) void pass2_kernel(const int2* __restrict__ staging,
                                                    const int* __restrict__ gcursor,
                                                    int* __restrict__ begs,
                                                    int* __restrict__ ends,
                                                    int2* __restrict__ edata) {
  __shared__ int lhist[1024];
  __shared__ int lcur[1024];
  __shared__ int psum[256];
  const int b = blockIdx.x;
  const int tid = threadIdx.x;
  const int base = b * BCAP;
  const int cnt  = gcursor[b] - base;

  for (int i = tid; i < 1024; i += 256) lhist[i] = 0;
  __syncthreads();
  for (int i = tid; i < cnt; i += 256)
    atomicAdd(&lhist[staging[base + i].x & 1023], 1);
  __syncthreads();
  int s0 = lhist[4 * tid], s1 = lhist[4 * tid + 1];
  int s2 = lhist[4 * tid + 2], s3 = lhist[4 * tid + 3];
  int tot = s0 + s1 + s2 + s3;
  psum[tid] = tot;
  __syncthreads();
  for (int off = 1; off < 256; off <<= 1) {
    int t = (tid >= off) ? psum[tid - off] : 0;
    __syncthreads();
    psum[tid] += t;
    __syncthreads();
  }
  int o0 = base + psum[tid] - tot;
  int o1 = o0 + s0, o2 = o1 + s1, o3 = o2 + s2;
  const int nodeb = b * 1024;
  begs[nodeb + 4 * tid]     = o0;  ends[nodeb + 4 * tid]     = o1;  lcur[4 * tid]     = o0;
  begs[nodeb + 4 * tid + 1] = o1;  ends[nodeb + 4 * tid + 1] = o2;  lcur[4 * tid + 1] = o1;
  begs[nodeb + 4 * tid + 2] = o2;  ends[nodeb + 4 * tid + 2] = o3;  lcur[4 * tid + 2] = o2;
  begs[nodeb + 4 * tid + 3] = o3;  ends[nodeb + 4 * tid + 3] = o3 + s3;  lcur[4 * tid + 3] = o3;
  __syncthreads();
  for (int i = tid; i < cnt; i += 256) {
    int2 r = staging[base + i];
    int pos = atomicAdd(&lcur[r.x & 1023], 1);
    int s  = r.x >> 12;
    int et = (r.x >> 10) & 3;
    int2 outr;
    outr.x = (s << 8) + (et << 6);              // src*256 + et*64
    outr.y = r.y;                               // norm f32 bits
    edata[pos] = outr;
  }
}

// ---------------------------------------------------------------------------
// Weight prep (+ gcursor init piggybacked on block 0):
//   Wcat0 [64,128] | WcatR[3][32,128] | Mt [2][128][128] = 0.125*wp@wt^T |
//   W1c [256][64] = Wp-block @ w1
// ---------------------------------------------------------------------------
__global__ __launch_bounds__(256) void wprep_kernel(
    const float* __restrict__ bases0, const float* __restrict__ coef0,
    const float* __restrict__ wself0,
    const float* __restrict__ bases_r, const float* __restrict__ coef_r,
    const float* __restrict__ wself_r,
    const float* __restrict__ wp_u, const float* __restrict__ wp_i,
    const float* __restrict__ wt_u, const float* __restrict__ wt_i,
    const float* __restrict__ w1,
    float* __restrict__ Wbuf, int* __restrict__ gcursor) {
  if (blockIdx.x == 0 && threadIdx.x < NBUCK)
    gcursor[threadIdx.x] = threadIdx.x * BCAP;
  int idx = blockIdx.x * 256 + threadIdx.x;
  if (idx < 8192) {                                      // Wcat0: [64][128]
    int i = idx >> 7, j = idx & 127;
    float v;
    if (j < 96) {
      int r = j >> 5, f = j & 31;
      v = coef0[r * 2 + 0] * bases0[0 * 2048 + i * 32 + f]
        + coef0[r * 2 + 1] * bases0[1 * 2048 + i * 32 + f];
    } else {
      v = wself0[i * 32 + (j - 96)];
    }
    Wbuf[idx] = v;
    return;
  }
  int idx2 = idx - 8192;
  if (idx2 < 3 * 4096) {                                 // WcatR[l]: [32][128]
    int l = idx2 >> 12, rem = idx2 & 4095;
    int i = rem >> 7, j = rem & 127;
    float v;
    if (j < 96) {
      int r = j >> 5, f = j & 31;
      v = coef_r[l * 6 + r * 2 + 0] * bases_r[l * 2048 + 0 * 1024 + i * 32 + f]
        + coef_r[l * 6 + r * 2 + 1] * bases_r[l * 2048 + 1 * 1024 + i * 32 + f];
    } else {
      v = wself_r[l * 1024 + i * 32 + (j - 96)];
    }
    Wbuf[idx] = v;
    return;
  }
  int idx3 = idx2 - 12288;
  if (idx3 < 32768) {                                    // Mt[side][kk][k]
    int side = idx3 >> 14;
    int r = idx3 & 16383;
    int kk = r >> 7, k = r & 127;
    const float* wp = side ? wp_i : wp_u;
    const float* wt = side ? wt_i : wt_u;
    float acc = 0.f;
#pragma unroll 8
    for (int j = 0; j < 64; ++j)
      acc = fmaf(wp[k * 64 + j], wt[kk * 64 + j], acc);
    Wbuf[idx] = acc * 0.125f;                            // /sqrt(PH) folded
    return;
  }
  int idx4 = idx3 - 32768;
  if (idx4 < 16384) {                                    // W1c[k'][t]
    int kp = idx4 >> 6, t = idx4 & 63;
    int side = kp >> 7, k = kp & 127;
    const float* wp = side ? wp_i : wp_u;
    float acc = 0.f;
#pragma unroll 8
    for (int j = 0; j < 64; ++j)
      acc = fmaf(wp[k * 64 + j], w1[(side * 64 + j) * 64 + t], acc);
    Wbuf[idx] = acc;
  }
}

// wprep2: MFMA B-fragments, bf16 hi + residual lo (layouts as round 11).
__global__ __launch_bounds__(256) void wprep2_kernel(const float* __restrict__ Wbuf,
                                                     unsigned short* __restrict__ Whi,
                                                     unsigned short* __restrict__ Wlo) {
  int e = blockIdx.x * 256 + threadIdx.x;
  if (e >= 20480) return;
  float v;
  if (e < 8192) {                    // layer 0, K=64, 128 out cols
    int j = e & 7, l = (e >> 3) & 63, c = (e >> 9) & 7, q = e >> 12;
    int k   = q * 32 + (l >> 4) * 8 + j;
    int col = c * 16 + (l & 15);
    v = Wbuf[k * 128 + col];
  } else {                           // layers 1-3, K=128, 32 out cols
    int e2 = e - 8192;
    int lay = e2 >> 12, r = e2 & 4095;
    int j = r & 7, l = (r >> 3) & 63, qc = r >> 9;       // 0..7
    int q = qc >> 1, c = qc & 1;
    int k = q * 32 + (l >> 4) * 8 + j;                   // 0..127
    int o = c * 16 + (l & 15);                           // 0..31
    const float* Wc = Wbuf + 8192 + lay * 4096;          // WcatR[lay][32][128]
    v = (k < 96) ? Wc[(k & 31) * 128 + (k >> 5) * 32 + o]
                 : Wc[(k - 96) * 128 + 96 + o];
  }
  unsigned short hi = f2bf(v);
  Whi[e] = hi;
  Wlo[e] = f2bf(v - bf2f(hi));
}

// ---------------------------------------------------------------------------
// Layer-0 MFMA transform: x[N,64] (f32, hi/lo split in-register) @
// Wcat0[64,128] -> Tb0 [N][128] bf16 (msgs [0,96), self [96,128)).
// ---------------------------------------------------------------------------
__global__ __launch_bounds__(256) void transform_l0_kernel(
    const float* __restrict__ x,
    const unsigned short* __restrict__ Whi, const unsigned short* __restrict__ Wlo,
    unsigned short* __restrict__ Tb0) {
  __shared__ float C[64][129];
  const int tid = threadIdx.x;
  const int wv = tid >> 6, l = tid & 63;
  const int l15 = l & 15, kg = l >> 4;
  const int row = blockIdx.x * 64 + wv * 16 + l15;

  short8v ah[2], al[2];
#pragma unroll
  for (int q = 0; q < 2; ++q) {
    const float* xp = x + (size_t)row * 64 + q * 32 + kg * 8;
    const float4 v0 = *reinterpret_cast<const float4*>(xp);
    const float4 v1 = *reinterpret_cast<const float4*>(xp + 4);
    const float vv[8] = {v0.x, v0.y, v0.z, v0.w, v1.x, v1.y, v1.z, v1.w};
#pragma unroll
    for (int f = 0; f < 8; ++f) {
      const unsigned short h = f2bf(vv[f]);
      ah[q][f] = (short)h;
      al[q][f] = (short)f2bf(vv[f] - bf2f(h));
    }
  }

#pragma unroll
  for (int c = 0; c < 8; ++c) {
    f32x4 a = {0.f, 0.f, 0.f, 0.f};
#pragma unroll
    for (int q = 0; q < 2; ++q) {
      const size_t fb = ((size_t)(q * 8 + c) * 64 + l) * 8;
      const short8v bh = *reinterpret_cast<const short8v*>(Whi + fb);
      const short8v bl = *reinterpret_cast<const short8v*>(Wlo + fb);
      a = __builtin_amdgcn_mfma_f32_16x16x32_bf16(ah[q], bh, a, 0, 0, 0);
      a = __builtin_amdgcn_mfma_f32_16x16x32_bf16(al[q], bh, a, 0, 0, 0);
      a = __builtin_amdgcn_mfma_f32_16x16x32_bf16(ah[q], bl, a, 0, 0, 0);
    }
    // C/D layout [verified]: col = lane&15, row_in_tile = (lane>>4)*4 + reg
#pragma unroll
    for (int r = 0; r < 4; ++r)
      C[wv * 16 + kg * 4 + r][c * 16 + l15] = a[r];
  }
  __syncthreads();

  const int row64 = tid & 63, q = tid >> 6;
  const int node = blockIdx.x * 64 + row64;
#pragma unroll
  for (int v = 0; v < 4; ++v) {
    const int cb = q * 32 + v * 8;
    uint4 pk;
    pk.x = (unsigned)f2bf(C[row64][cb + 0]) | ((unsigned)f2bf(C[row64][cb + 1]) << 16);
    pk.y = (unsigned)f2bf(C[row64][cb + 2]) | ((unsigned)f2bf(C[row64][cb + 3]) << 16);
    pk.z = (unsigned)f2bf(C[row64][cb + 4]) | ((unsigned)f2bf(C[row64][cb + 5]) << 16);
    pk.w = (unsigned)f2bf(C[row64][cb + 6]) | ((unsigned)f2bf(C[row64][cb + 7]) << 16);
    *reinterpret_cast<uint4*>(Tb0 + (size_t)node * 128 + cb) = pk;
  }
}

// ---------------------------------------------------------------------------
// Layer-0 aggregate: gathers pre-transformed messages from Tb0 (64B/edge),
// adds bf16 self (row bytes [192,256)) + bias, tanh -> hcat slot0 + hbA.
// (8 lanes/node already cover full 64B lines per wave-op on both outputs.)
// ---------------------------------------------------------------------------
__global__ __launch_bounds__(256) void aggregate_l0_kernel(
    const unsigned short* __restrict__ Tb0,
    const int* __restrict__ begs, const int* __restrict__ ends,
    const int2* __restrict__ edata, const float* __restrict__ bias,
    float* __restrict__ hcat, unsigned short* __restrict__ hbA) {
  const int node = blockIdx.x * 32 + (threadIdx.x >> 3);
  const int f4   = (threadIdx.x & 7) * 4;
  const int loff = f4 * 2;
  const char* Tbc = (const char*)Tb0;
  const int beg = begs[node];
  const int end = ends[node];
  const ushort4 sb = *reinterpret_cast<const ushort4*>(Tbc + (size_t)node * 256 + 192 + loff);
  const float4 bv  = *reinterpret_cast<const float4*>(&bias[f4]);
  float ax = bf2f(sb.x) + bv.x, ay = bf2f(sb.y) + bv.y;
  float az = bf2f(sb.z) + bv.z, aw = bf2f(sb.w) + bv.w;

  int k = beg;
  for (; k + 8 <= end; k += 8) {
    int2 ed[8];
#pragma unroll
    for (int u = 0; u < 8; ++u) ed[u] = edata[k + u];
    ushort4 mv[8];
#pragma unroll
    for (int u = 0; u < 8; ++u)
      mv[u] = *reinterpret_cast<const ushort4*>(Tbc + ed[u].x + loff);
#pragma unroll
    for (int u = 0; u < 8; ++u) {
      const float nm = __int_as_float(ed[u].y);
      ax = fmaf(bf2f(mv[u].x), nm, ax);
      ay = fmaf(bf2f(mv[u].y), nm, ay);
      az = fmaf(bf2f(mv[u].z), nm, az);
      aw = fmaf(bf2f(mv[u].w), nm, aw);
    }
  }
  for (; k < end; ++k) {
    int2 e0 = edata[k];
    const float nm = __int_as_float(e0.y);
    ushort4 m0 = *reinterpret_cast<const ushort4*>(Tbc + e0.x + loff);
    ax = fmaf(bf2f(m0.x), nm, ax);
    ay = fmaf(bf2f(m0.y), nm, ay);
    az = fmaf(bf2f(m0.z), nm, az);
    aw = fmaf(bf2f(m0.w), nm, aw);
  }
  float4 o;
  o.x = tanhf(ax); o.y = tanhf(ay); o.z = tanhf(az); o.w = tanhf(aw);
  *reinterpret_cast<float4*>(&hcat[(size_t)node * 128 + f4]) = o;
  ushort4 h;
  h.x = f2bf(o.x); h.y = f2bf(o.y); h.z = f2bf(o.z); h.w = f2bf(o.w);
  *reinterpret_cast<ushort4*>(hbA + (size_t)node * 32 + f4) = h;
}

// ---------------------------------------------------------------------------
// FUSED layers 1-3: 32 nodes/block, 8 lanes/node gather from compact
// hbX [N][32]b; per-relation sums -> LDS bf16 [32][136]; MFMA [128->32]
// (W hi/lo); tanh+bias epilogue with FULL-LINE writes: thread t<128 ->
// (node=t>>2, q=t&3) writes a contiguous 32B hcat chunk + 16B hbY chunk,
// so each wave-op covers whole 64B lines (fixes the r13/r17 partial-line
// write amplification: WRITE 128.8MB -> ~39MB).
// ---------------------------------------------------------------------------
__global__ __launch_bounds__(256, 8) void agg_tf_kernel(
    const unsigned short* __restrict__ hbX,
    const int* __restrict__ begs, const int* __restrict__ ends,
    const int2* __restrict__ edata,
    const unsigned short* __restrict__ Whi, const unsigned short* __restrict__ Wlo,
    const float* __restrict__ bias,
    float* __restrict__ hcatSlot, unsigned short* __restrict__ hbY) {
  __shared__ __align__(16) unsigned short sld[32][136];
  __shared__ float C[32][33];
  const int tid = threadIdx.x;

  // ---- phase A: 8 lanes/node, 4 features (8B) each ----
  {
    const int nl   = tid >> 3;                 // 0..31
    const int node = blockIdx.x * 32 + nl;
    const int f4   = (tid & 7) * 4;
    const int loff = f4 * 2;
    const char* hbc = (const char*)hbX;
    const int beg = begs[node], end = ends[node];
    float a0x = 0.f, a0y = 0.f, a0z = 0.f, a0w = 0.f;
    float a1x = 0.f, a1y = 0.f, a1z = 0.f, a1w = 0.f;
    float a2x = 0.f, a2y = 0.f, a2z = 0.f, a2w = 0.f;

    int k = beg;
    for (; k + 8 <= end; k += 8) {
      int2 ed[8];
#pragma unroll
      for (int u = 0; u < 8; ++u) ed[u] = edata[k + u];
      ushort4 mv[8];
#pragma unroll
      for (int u = 0; u < 8; ++u)
        mv[u] = *reinterpret_cast<const ushort4*>(hbc + ((ed[u].x >> 2) & ~63) + loff);
#pragma unroll
      for (int u = 0; u < 8; ++u) {
        const int et = (ed[u].x >> 6) & 3;
        const float nm = __int_as_float(ed[u].y);
        const float n0 = (et == 0) ? nm : 0.f;
        const float n1 = (et == 1) ? nm : 0.f;
        const float n2 = (et == 2) ? nm : 0.f;
        const float vx = bf2f(mv[u].x), vy = bf2f(mv[u].y);
        const float vz = bf2f(mv[u].z), vw = bf2f(mv[u].w);
        a0x = fmaf(vx, n0, a0x); a0y = fmaf(vy, n0, a0y);
        a0z = fmaf(vz, n0, a0z); a0w = fmaf(vw, n0, a0w);
        a1x = fmaf(vx, n1, a1x); a1y = fmaf(vy, n1, a1y);
        a1z = fmaf(vz, n1, a1z); a1w = fmaf(vw, n1, a1w);
        a2x = fmaf(vx, n2, a2x); a2y = fmaf(vy, n2, a2y);
        a2z = fmaf(vz, n2, a2z); a2w = fmaf(vw, n2, a2w);
      }
    }
    for (; k < end; ++k) {
      int2 e0 = edata[k];
      const int et = (e0.x >> 6) & 3;
      const float nm = __int_as_float(e0.y);
      const float n0 = (et == 0) ? nm : 0.f;
      const float n1 = (et == 1) ? nm : 0.f;
      const float n2 = (et == 2) ? nm : 0.f;
      ushort4 m0 = *reinterpret_cast<const ushort4*>(hbc + ((e0.x >> 2) & ~63) + loff);
      const float vx = bf2f(m0.x), vy = bf2f(m0.y), vz = bf2f(m0.z), vw = bf2f(m0.w);
      a0x = fmaf(vx, n0, a0x); a0y = fmaf(vy, n0, a0y);
      a0z = fmaf(vz, n0, a0z); a0w = fmaf(vw, n0, a0w);
      a1x = fmaf(vx, n1, a1x); a1y = fmaf(vy, n1, a1y);
      a1z = fmaf(vz, n1, a1z); a1w = fmaf(vw, n1, a1w);
      a2x = fmaf(vx, n2, a2x); a2y = fmaf(vy, n2, a2y);
      a2z = fmaf(vz, n2, a2z); a2w = fmaf(vw, n2, a2w);
    }
    ushort4 s0, s1, s2;
    s0.x = f2bf(a0x); s0.y = f2bf(a0y); s0.z = f2bf(a0z); s0.w = f2bf(a0w);
    s1.x = f2bf(a1x); s1.y = f2bf(a1y); s1.z = f2bf(a1z); s1.w = f2bf(a1w);
    s2.x = f2bf(a2x); s2.y = f2bf(a2y); s2.z = f2bf(a2z); s2.w = f2bf(a2w);
    *reinterpret_cast<ushort4*>(&sld[nl][f4])      = s0;
    *reinterpret_cast<ushort4*>(&sld[nl][32 + f4]) = s1;
    *reinterpret_cast<ushort4*>(&sld[nl][64 + f4]) = s2;
    *reinterpret_cast<ushort4*>(&sld[nl][96 + f4]) =
        *reinterpret_cast<const ushort4*>(hbX + (size_t)node * 32 + f4);
  }
  __syncthreads();

  // ---- phase B: 4 waves, wave w -> (row-half w&1, c-tile w>>1) ----
  {
    const int w = tid >> 6, l = tid & 63;
    const int rg = w & 1, c = w >> 1;
    const int l15 = l & 15, kg = l >> 4;
    const int row = rg * 16 + l15;
    short8v af[4];
#pragma unroll
    for (int q = 0; q < 4; ++q)
      af[q] = *reinterpret_cast<const short8v*>(&sld[row][q * 32 + kg * 8]);
    f32x4 a = {0.f, 0.f, 0.f, 0.f};
#pragma unroll
    for (int q = 0; q < 4; ++q) {
      const size_t fb = ((size_t)(q * 2 + c) * 64 + l) * 8;
      const short8v bh = *reinterpret_cast<const short8v*>(Whi + fb);
      const short8v bl = *reinterpret_cast<const short8v*>(Wlo + fb);
      a = __builtin_amdgcn_mfma_f32_16x16x32_bf16(af[q], bh, a, 0, 0, 0);
      a = __builtin_amdgcn_mfma_f32_16x16x32_bf16(af[q], bl, a, 0, 0, 0);
    }
    // C/D layout [verified]: col = lane&15, row_in_tile = (lane>>4)*4 + reg
#pragma unroll
    for (int r = 0; r < 4; ++r)
      C[rg * 16 + kg * 4 + r][c * 16 + l15] = a[r];
  }
  __syncthreads();

  // ---- epilogue: full-line writes. t<128: node=t>>2, q=t&3 (8 cols) ----
  if (tid < 128) {
    const int node32 = tid >> 2, q = tid & 3;
    const int node = blockIdx.x * 32 + node32;
    float z[8];
#pragma unroll
    for (int v = 0; v < 8; ++v)
      z[v] = tanhf(C[node32][q * 8 + v] + bias[q * 8 + v]);
    float4 f0 = {z[0], z[1], z[2], z[3]};
    float4 f1 = {z[4], z[5], z[6], z[7]};
    float* hp = hcatSlot + (size_t)node * 128 + q * 8;
    *reinterpret_cast<float4*>(hp)     = f0;     // 32B contiguous per lane:
    *reinterpret_cast<float4*>(hp + 4) = f1;     // lanes 4n..4n+3 = full lines
    if (hbY) {
      uint4 pk;
      pk.x = (unsigned)f2bf(z[0]) | ((unsigned)f2bf(z[1]) << 16);
      pk.y = (unsigned)f2bf(z[2]) | ((unsigned)f2bf(z[3]) << 16);
      pk.z = (unsigned)f2bf(z[4]) | ((unsigned)f2bf(z[5]) << 16);
      pk.w = (unsigned)f2bf(z[6]) | ((unsigned)f2bf(z[7]) << 16);
      *reinterpret_cast<uint4*>(hbY + (size_t)node * 32 + q * 8) = pk;
    }
  }
}

// ---------------------------------------------------------------------------
// Fused per-graph tail (unchanged; XCD-chunked graph swizzle).
// ---------------------------------------------------------------------------
__global__ __launch_bounds__(256) void pool_head_kernel(
    const float* __restrict__ hcat, const int* __restrict__ ntype,
    const float* __restrict__ Mt,   // [2][128][128], 0.125 folded
    const float* __restrict__ W1c,  // [256][64]
    const float* __restrict__ b1,
    const float* __restrict__ w2, const float* __restrict__ b2,
    float* __restrict__ out, float* __restrict__ tl) {
  __shared__ float hl[GS * 129];
  __shared__ float scr[1024];
  __shared__ float av2[256];
  __shared__ float red[4];
  __shared__ float cnts[4];
  __shared__ int   snt[64];
  __shared__ int   sntp[64];

  const int g    = (blockIdx.x & 7) * (BB / 8) + (blockIdx.x >> 3);  // XCD chunk
  const int gp   = (g + BB - 1) & (BB - 1);
  const int tid  = threadIdx.x;
  const int lane = tid & 63;

  const float* hg  = hcat + (size_t)g  * (GS * 128);
  const float* hp  = hcat + (size_t)gp * (GS * 128);
  const int*   ntg = ntype + g  * GS;
  const int*   ntp = ntype + gp * GS;

  if (tid < 64) {
    snt[tid] = (tid < GS) ? ntg[tid] : 99;
    unsigned long long bu = __ballot(snt[tid] == 0);
    unsigned long long bi = __ballot(snt[tid] == 1);
    if (lane == 0) {
      cnts[0] = 1.f / ((float)__popcll(bu) + 1e-8f);
      cnts[1] = 1.f / ((float)__popcll(bi) + 1e-8f);
    }
  } else if (tid < 128) {
    sntp[lane] = (lane < GS) ? ntp[lane] : 99;
    unsigned long long bp = __ballot(sntp[lane] == 1);
    if (lane == 0) cnts[2] = 1.f / ((float)__popcll(bp) + 1e-8f);
  }

  {
    const int rowg = tid >> 5;
    const int kq   = (tid & 31) * 4;
    float spx = 0.f, spy = 0.f, spz = 0.f, spw = 0.f;
#pragma unroll
    for (int p = 0; p < 7; ++p) {
      const int r = rowg + 8 * p;
      if (r < GS) {
        const float4 v = *reinterpret_cast<const float4*>(hg + r * 128 + kq);
        hl[r * 129 + kq + 0] = v.x;
        hl[r * 129 + kq + 1] = v.y;
        hl[r * 129 + kq + 2] = v.z;
        hl[r * 129 + kq + 3] = v.w;
        if (ntp[r] == 1) {
          const float4 w = *reinterpret_cast<const float4*>(hp + r * 128 + kq);
          spx += w.x; spy += w.y; spz += w.z; spw += w.w;
        }
      }
    }
    scr[rowg * 128 + kq + 0] = spx;
    scr[rowg * 128 + kq + 1] = spy;
    scr[rowg * 128 + kq + 2] = spz;
    scr[rowg * 128 + kq + 3] = spw;
  }
  __syncthreads();

  if (tid < 128) {
    const int kf = tid;
    float su = 0.f, si = 0.f;
#pragma unroll
    for (int r = 0; r < GS; ++r) {
      const float v = hl[r * 129 + kf];
      if (snt[r] == 0) su += v; else si += v;
    }
    float sp = 0.f;
#pragma unroll
    for (int rg = 0; rg < 8; ++rg) sp += scr[rg * 128 + kf];
    const float auk = su * cnts[0];
    const float aik = si * cnts[1];
    const float apk = sp * cnts[2];
    av2[kf]       = auk;
    av2[128 + kf] = aik;
    float d1 = (auk - aik) * (auk - aik);
    float d2 = (auk - apk) * (auk - apk);
    for (int o = 32; o; o >>= 1) {
      d1 += __shfl_xor(d1, o);
      d2 += __shfl_xor(d2, o);
    }
    if (lane == 0) { red[tid >> 6] = d1; red[2 + (tid >> 6)] = d2; }
  }
  __syncthreads();

  {
    const int side = tid >> 7, kf = tid & 127;
    const float* M  = Mt + (size_t)side * 16384 + kf;
    const float* av = av2 + side * 128;
    float a0 = 0.f, a1 = 0.f, a2 = 0.f, a3 = 0.f;
#pragma unroll 4
    for (int kk = 0; kk < 128; kk += 4) {
      a0 = fmaf(M[(kk + 0) * 128], av[kk + 0], a0);
      a1 = fmaf(M[(kk + 1) * 128], av[kk + 1], a1);
      a2 = fmaf(M[(kk + 2) * 128], av[kk + 2], a2);
      a3 = fmaf(M[(kk + 3) * 128], av[kk + 3], a3);
    }
    scr[tid] = (a0 + a1) + (a2 + a3);
  }
  if (tid == 0) tl[g] = fmaxf(0.f, (red[0] + red[1]) - (red[2] + red[3]) + 1.0f);
  __syncthreads();

  if (tid < 128) {
    const int side = tid >> 6;
    const float* q = scr + side * 128;
    float v = -1e9f;
    bool msk = false;
    if (lane < GS) {
      msk = (snt[lane] == side);
      float a0 = 0.f, a1 = 0.f;
#pragma unroll 8
      for (int k = 0; k < 128; k += 2) {
        a0 = fmaf(hl[lane * 129 + k], q[k], a0);
        a1 = fmaf(hl[lane * 129 + k + 1], q[k + 1], a1);
      }
      v = msk ? (a0 + a1) : -1e9f;
    }
    float m = v;
    for (int o = 32; o; o >>= 1) m = fmaxf(m, __shfl_xor(m, o));
    float e = (lane < GS && msk) ? expf(v - m) : 0.f;
    float z = e;
    for (int o = 32; o; o >>= 1) z += __shfl_xor(z, o);
    const float invz = 1.f / (z + 1e-8f);
    if (lane < GS) scr[256 + side * 64 + lane] = e * invz;
  }
  __syncthreads();

  {
    const int side = tid >> 7, kf = tid & 127;
    const float* a = scr + 256 + side * 64;
    float acc = 0.f;
#pragma unroll
    for (int nl = 0; nl < GS; ++nl)
      acc = fmaf(a[nl], hl[nl * 129 + kf], acc);
    scr[384 + side * 128 + kf] = acc;
  }
  __syncthreads();

  {
    const int j = tid & 63, c = tid >> 6;
    const float* Wc = W1c + (size_t)c * 64 * 64 + j;
    const float* cv = scr + 384 + c * 64;
    float a0 = 0.f, a1 = 0.f, a2 = 0.f, a3 = 0.f;
#pragma unroll 4
    for (int k = 0; k < 64; k += 4) {
      a0 = fmaf(Wc[(k + 0) * 64], cv[k + 0], a0);
      a1 = fmaf(Wc[(k + 1) * 64], cv[k + 1], a1);
      a2 = fmaf(Wc[(k + 2) * 64], cv[k + 2], a2);
      a3 = fmaf(Wc[(k + 3) * 64], cv[k + 3], a3);
    }
    scr[640 + c * 64 + j] = (a0 + a1) + (a2 + a3);
  }
  __syncthreads();

  if (tid < 64) {
    const float z1 = fmaxf(b1[tid] + scr[640 + tid] + scr[704 + tid] +
                           scr[768 + tid] + scr[832 + tid], 0.f);
    float p = z1 * w2[tid];
    for (int o = 32; o; o >>= 1) p += __shfl_xor(p, o);
    if (tid == 0) out[g] = 1.f / (1.f + expf(-(p + b2[0])));
  }
}

__global__ __launch_bounds__(256) void tl_reduce_kernel(const float* __restrict__ tl,
                                                        float* __restrict__ out) {
  __shared__ float s[256];
  float acc = 0.f;
  for (int i = threadIdx.x; i < BB; i += 256) acc += tl[i];
  s[threadIdx.x] = acc;
  __syncthreads();
  for (int off = 128; off > 0; off >>= 1) {
    if (threadIdx.x < off) s[threadIdx.x] += s[threadIdx.x + off];
    __syncthreads();
  }
  if (threadIdx.x == 0) out[BB] = s[0] * (1.f / (float)BB);
}

// ---------------------------------------------------------------------------
extern "C" void kernel_launch(void* const* d_in, const int* in_sizes, int n_in,
                              void* d_out, int out_size, void* d_ws, size_t ws_size,
                              hipStream_t stream) {
  const float* x        = (const float*)d_in[0];
  const float* edge_nrm = (const float*)d_in[1];
  const int*   src      = (const int*)d_in[2];
  const int*   dst      = (const int*)d_in[3];
  const int*   etype    = (const int*)d_in[4];
  // d_in[5] = graph_id: unused (contiguous 50-node graphs)
  const int*   ntype    = (const int*)d_in[6];
  const float* bases0   = (const float*)d_in[7];
  const float* coef0    = (const float*)d_in[8];
  const float* wself0   = (const float*)d_in[9];
  const float* bias0    = (const float*)d_in[10];
  const float* bases_r  = (const float*)d_in[11];
  const float* coef_r   = (const float*)d_in[12];
  const float* wself_r  = (const float*)d_in[13];
  const float* bias_r   = (const float*)d_in[14];
  const float* wp_u     = (const float*)d_in[15];
  const float* wt_u     = (const float*)d_in[16];
  const float* wp_i     = (const float*)d_in[17];
  const float* wt_i     = (const float*)d_in[18];
  const float* w1       = (const float*)d_in[19];
  const float* b1       = (const float*)d_in[20];
  const float* w2       = (const float*)d_in[21];
  const float* b2       = (const float*)d_in[22];
  float* out = (float*)d_out;

  // workspace layout (regions verified disjoint):
  //   hcat : N*128 f32 [0, N*512B); head doubles as CSR 'staging' (dead
  //          until aggregate_l0 writes hcat, which runs after pass2).
  //   R    : Tb0 bf16 [0, N*256B) | hbA [N*256, N*320) | hbB [N*320, N*384)
  //   edata: ESLOTS int2 (padded slot space) | begs,ends: N each |
  //   gcursor: 256 | Wbuf: 69632 f32 | Whi/Wlo: 2*20480 bf16 | tl: B
  float*          hcat = (float*)d_ws;                       // N*128
  int2*           staging = (int2*)hcat;                     // CSR-build alias
  float*          R    = hcat + (size_t)NN * 128;            // N*128
  unsigned short* Tb0  = (unsigned short*)R;                 // N*128 bf16
  unsigned short* hbA  = Tb0 + (size_t)NN * 128;             // N*32 bf16
  unsigned short* hbB  = hbA + (size_t)NN * 32;              // N*32 bf16
  int2*  edata   = (int2*)(R + (size_t)NN * 128);            // ESLOTS int2
  int*   begs    = (int*)(edata + ESLOTS);                   // N
  int*   ends    = begs + NN;                                // N
  int*   gcursor = ends + NN;                                // 256
  float* Wbuf    = (float*)(gcursor + 256);                  // 69632 f32
  unsigned short* Whi = (unsigned short*)(Wbuf + 69632);     // 20480 bf16
  unsigned short* Wlo = Whi + 20480;                         // 20480 bf16
  float* tl      = Wbuf + 69632 + 10240;                     // B

  size_t need = ((size_t)NN * 128 * 2 + ESLOTS * 2 + 2 * NN +
                 256 + 69632 + 10240 + BB) * 4;
  if (ws_size < need) return;

  // --- weights (+gcursor init) + MFMA fragment packing ---
  wprep_kernel<<<(69632 + 255) / 256, 256, 0, stream>>>(
      bases0, coef0, wself0, bases_r, coef_r, wself_r,
      wp_u, wp_i, wt_u, wt_i, w1, Wbuf, gcursor);
  wprep2_kernel<<<80, 256, 0, stream>>>(Wbuf, Whi, Wlo);

  // --- CSR build ---
  pass1_kernel<<<EE / CHUNK, 256, 0, stream>>>(src, dst, etype, edge_nrm,
                                               gcursor, staging);
  pass2_kernel<<<NBUCK, 256, 0, stream>>>(staging, gcursor, begs, ends, edata);

  // --- layer 0: MFMA transform + gather-aggregate ---
  transform_l0_kernel<<<NN / 64, 256, 0, stream>>>(x, Whi, Wlo, Tb0);
  aggregate_l0_kernel<<<NN / 32, 256, 0, stream>>>(Tb0, begs, ends, edata,
                                                   bias0, hcat, hbA);

  // --- layers 1..3: fused gather + per-relation sums + MFMA + tanh ---
  agg_tf_kernel<<<NN / 32, 256, 0, stream>>>(
      hbA, begs, ends, edata, Whi + 8192, Wlo + 8192, bias_r,
      hcat + 32, hbB);
  agg_tf_kernel<<<NN / 32, 256, 0, stream>>>(
      hbB, begs, ends, edata, Whi + 12288, Wlo + 12288, bias_r + 32,
      hcat + 64, hbA);
  agg_tf_kernel<<<NN / 32, 256, 0, stream>>>(
      hbA, begs, ends, edata, Whi + 16384, Wlo + 16384, bias_r + 64,
      hcat + 96, nullptr);

  // --- fused per-graph tail ---
  pool_head_kernel<<<BB, 256, 0, stream>>>(hcat, ntype,
                                           Wbuf + 20480, Wbuf + 53248,
                                           b1, w2, b2, out, tl);
  tl_reduce_kernel<<<1, 256, 0, stream>>>(tl, out);
}